// Round 15
// baseline (2030.664 us; speedup 1.0000x reference)
//
#include <hip/hip_runtime.h>
#include <stdint.h>

typedef __attribute__((ext_vector_type(8))) short short8;
typedef __attribute__((ext_vector_type(4))) short short4v;
typedef __attribute__((ext_vector_type(4))) float f32x4;

#define DEVINL __device__ __forceinline__

DEVINL unsigned short f2bf(float x) {
  uint32_t b = __float_as_uint(x);
  b += 0x7fffu + ((b >> 16) & 1u);
  return (unsigned short)(b >> 16);
}
DEVINL float bf2f(unsigned short u) {
  return __uint_as_float(((uint32_t)u) << 16);
}

DEVINL void gll16(const void* g, void* l) {
  __builtin_amdgcn_global_load_lds(
      (const __attribute__((address_space(1))) uint32_t*)g,
      (__attribute__((address_space(3))) uint32_t*)l, 16, 0, 0);
}

// one launch converts all three weight matrices to bf16
__global__ void cvt_w3(const float* __restrict__ W1, const float* __restrict__ W2,
                       const float* __restrict__ Wq, unsigned short* __restrict__ o1,
                       unsigned short* __restrict__ o2, unsigned short* __restrict__ oq,
                       int n1, int n2, int nq) {
  int i = blockIdx.x * blockDim.x + threadIdx.x;
  const int st = gridDim.x * blockDim.x;
  const int tot = n1 + n2 + nq;
  for (; i < tot; i += st) {
    if (i < n1)
      o1[i] = f2bf(W1[i]);
    else if (i < n1 + n2)
      o2[i - n1] = f2bf(W2[i - n1]);
    else
      oq[i - n1 - n2] = f2bf(Wq[i - n1 - n2]);
  }
}

// wave-per-row: out_row = bf16(in_row / (||in_row|| + eps))
template <int D>
__global__ __launch_bounds__(256) void norm_rows_f32(
    const float* __restrict__ in, unsigned short* __restrict__ out, int nrows) {
  const int lane = threadIdx.x & 63;
  const int row = blockIdx.x * 4 + (threadIdx.x >> 6);
  if (row >= nrows) return;
  const float* r = in + (size_t)row * D;
  constexpr int NSEG = D / 256;
  f32x4 v[NSEG];
  float ssq = 0.f;
#pragma unroll
  for (int i = 0; i < NSEG; ++i) {
    v[i] = *(const f32x4*)(r + (i * 64 + lane) * 4);
#pragma unroll
    for (int j = 0; j < 4; ++j) ssq += v[i][j] * v[i][j];
  }
#pragma unroll
  for (int m = 32; m >= 1; m >>= 1) ssq += __shfl_xor(ssq, m, 64);
  const float sc = 1.0f / (sqrtf(ssq) + 1e-8f);
  unsigned short* o = out + (size_t)row * D;
#pragma unroll
  for (int i = 0; i < NSEG; ++i) {
    short4v u;
#pragma unroll
    for (int j = 0; j < 4; ++j) u[j] = (short)f2bf(v[i][j] * sc);
    *(short4v*)(o + (i * 64 + lane) * 4) = u;
  }
}

// wave-per-row: scale[row] = 1/(||bf16 row|| + eps)
template <int H>
__global__ __launch_bounds__(256) void rownorm_bf16(
    const unsigned short* __restrict__ in, float* __restrict__ scale, int nrows) {
  const int lane = threadIdx.x & 63;
  const int row = blockIdx.x * 4 + (threadIdx.x >> 6);
  if (row >= nrows) return;
  const unsigned short* r = in + (size_t)row * H;
  constexpr int NSEG = H / 512;
  float ssq = 0.f;
#pragma unroll
  for (int i = 0; i < NSEG; ++i) {
    short8 u = *(const short8*)(r + (i * 64 + lane) * 8);
#pragma unroll
    for (int j = 0; j < 8; ++j) {
      float f = bf2f((unsigned short)u[j]);
      ssq += f * f;
    }
  }
#pragma unroll
  for (int m = 32; m >= 1; m >>= 1) ssq += __shfl_xor(ssq, m, 64);
  if (lane == 0) scale[row] = 1.0f / (sqrtf(ssq) + 1e-8f);
}

// 128x256 SINGLE-buffer GEMM, 2 blocks/CU (16 waves/CU overlap — r5's
// validated mechanism at 256-class access efficiency). BK=64, 8 waves
// (2Mx4N), per-wave C = 64x64 (acc 4x4, ~88-110 VGPR). LDS = 48 KB single
// buffer: As[128][64] | Bs[256][64]. 176 LDS accesses per K-tile
// (8x16 reads + 48 writes) vs r5's 128 per HALF the FLOPs -> 1.45x better
// FLOP/access; at the r5-calibrated 12.2 cyc/access saturation this floors
// G1 at ~229 us.
// Per K-tile: {16 ds_read_b128 + 32 MFMA (compiler lgkmcnt); lgkmcnt(0)+
// s_barrier [all reads of tile t retired by every wave]; stage tile t+1
// (6 gll16, skipped on last iter); vmcnt(0); s_barrier [published]}.
// Single-buffer stall (HBM latency behind vmcnt(0)) is covered by the
// co-resident block on the same CU — blocks are barrier-independent.
// Race-freedom (r2/r6-class, simplest validated): reads of tile t retire
// before barrier-1 (explicit lgkmcnt(0)); writes of t+1 issued only after
// barrier-1; vmcnt(0)+barrier-2 publish before any tile-t+1 read.
// T2 involution swizzle (128B rows): stored 16B-unit at pos p of row r is
// global unit p^(r&7) (pre-swizzled global source keeps LDS linear for
// gll16); ds_read pos u^(r&7), r&7==lane&7 -> 0 conflicts (measured
// r5-r11). XCD-bijective blockIdx swizzle (grid %8==0).
template <bool SCALE, bool RELU, bool OUT_BF16>
__global__ __launch_bounds__(512, 4) void gemm_sb(
    const unsigned short* __restrict__ A, const unsigned short* __restrict__ Bw,
    const float* __restrict__ bias, const float* __restrict__ scaleArr,
    void* __restrict__ Cptr, int M, int N, int K) {
  __shared__ short lds[24576];  // As[128][64] (8192) | Bs[256][64] (16384)

  const int t = threadIdx.x;
  const int lane = t & 63;
  const int wid = t >> 6;   // 0..7
  const int wr = wid >> 2;  // 0..1  (64-row half of 128)
  const int wc = wid & 3;   // 0..3  (64-col quarter of 256)

  const int nwg = gridDim.x;
  const int bid = blockIdx.x;
  int wg = bid;
  if ((nwg & 7) == 0) wg = (bid & 7) * (nwg >> 3) + (bid >> 3);
  const int numBN = N >> 8;
  const int bm = wg / numBN;  // 128-row block
  const int bn = wg % numBN;  // 256-col block

  // Staging: load j covers row j*64 + (t>>3), 16B-unit pos t&7.
  // Pre-swizzled source: global unit = (t&7) ^ (row&7); row&7 == (t>>3)&7.
  const int rowS = t >> 3;  // 0..63
  const int usrc = ((t & 7) ^ (rowS & 7)) << 3;
  const unsigned short* sA0 = A + (size_t)(bm * 128 + rowS) * K + usrc;
  const unsigned short* sA1 = A + (size_t)(bm * 128 + 64 + rowS) * K + usrc;
  const unsigned short* sB0 = Bw + (size_t)(bn * 256 + rowS) * K + usrc;
  const unsigned short* sB1 = Bw + (size_t)(bn * 256 + 64 + rowS) * K + usrc;
  const unsigned short* sB2 = Bw + (size_t)(bn * 256 + 128 + rowS) * K + usrc;
  const unsigned short* sB3 = Bw + (size_t)(bn * 256 + 192 + rowS) * K + usrc;
  const int dA0 = t * 8, dA1 = 4096 + t * 8;
  const int dB0 = 8192 + t * 8, dB1 = 12288 + t * 8, dB2 = 16384 + t * 8,
            dB3 = 20480 + t * 8;

  // ds_read: row r, global unit u = kh*4+(lane>>4) -> pos u^(r&7); r&7==lane&7.
  const int sw = lane & 7;
  const int pA = (wr * 64 + (lane & 15)) * 64;
  const int pB = 8192 + (wc * 64 + (lane & 15)) * 64;
  const int pu0 = (((lane >> 4)) ^ sw) * 8;
  const int pu1 = ((4 | (lane >> 4)) ^ sw) * 8;

  f32x4 acc[4][4] = {};
  const int nt = K >> 6;

  // prologue: stage tile 0, publish
  gll16(sA0, &lds[dA0]);
  gll16(sA1, &lds[dA1]);
  gll16(sB0, &lds[dB0]);
  gll16(sB1, &lds[dB1]);
  gll16(sB2, &lds[dB2]);
  gll16(sB3, &lds[dB3]);
  asm volatile("s_waitcnt vmcnt(0)" ::: "memory");
  asm volatile("s_barrier" ::: "memory");

  for (int tt = 0; tt < nt; ++tt) {
    // ---- compute tile tt from the single buffer ----
    short8 a[4][2], b[4][2];
#pragma unroll
    for (int m = 0; m < 4; ++m) {
      a[m][0] = *(const short8*)&lds[pA + m * 1024 + pu0];
      a[m][1] = *(const short8*)&lds[pA + m * 1024 + pu1];
    }
#pragma unroll
    for (int n = 0; n < 4; ++n) {
      b[n][0] = *(const short8*)&lds[pB + n * 1024 + pu0];
      b[n][1] = *(const short8*)&lds[pB + n * 1024 + pu1];
    }
    __builtin_amdgcn_s_setprio(1);
#pragma unroll
    for (int ks = 0; ks < 2; ++ks)
#pragma unroll
      for (int m = 0; m < 4; ++m)
#pragma unroll
        for (int n = 0; n < 4; ++n)
          acc[m][n] = __builtin_amdgcn_mfma_f32_16x16x32_bf16(
              a[m][ks], b[n][ks], acc[m][n], 0, 0, 0);
    __builtin_amdgcn_s_setprio(0);
    // all of this wave's ds_reads retired before crossing; then block-wide sync
    asm volatile("s_waitcnt lgkmcnt(0)\n\ts_barrier" ::: "memory");
    // ---- stage tile tt+1 (skip on last iter; uniform branch) ----
    if (tt + 1 < nt) {
      const int kn = (tt + 1) * 64;
      gll16(sA0 + kn, &lds[dA0]);
      gll16(sA1 + kn, &lds[dA1]);
      gll16(sB0 + kn, &lds[dB0]);
      gll16(sB1 + kn, &lds[dB1]);
      gll16(sB2 + kn, &lds[dB2]);
      gll16(sB3 + kn, &lds[dB3]);
    }
    asm volatile("s_waitcnt vmcnt(0)" ::: "memory");
    asm volatile("s_barrier" ::: "memory");
  }

  // epilogue: frag row=(lane>>4)*4+j, col=lane&15
#pragma unroll
  for (int m = 0; m < 4; ++m) {
#pragma unroll
    for (int j = 0; j < 4; ++j) {
      const int rl = wr * 64 + m * 16 + ((lane >> 4) << 2) + j;
      const size_t row = (size_t)bm * 128 + rl;
      float sc = 1.0f;
      if constexpr (SCALE) sc = scaleArr[row];
#pragma unroll
      for (int n = 0; n < 4; ++n) {
        const int col = bn * 256 + wc * 64 + n * 16 + (lane & 15);
        float x = acc[m][n][j];
        if constexpr (SCALE) x *= sc;
        x += bias[col];
        if constexpr (RELU) x = fmaxf(x, 0.f);
        if constexpr (OUT_BF16)
          ((unsigned short*)Cptr)[row * (size_t)N + col] = f2bf(x);
        else
          ((float*)Cptr)[row * (size_t)N + col] = x;
      }
    }
  }
}

// 2-phase GEMM for G3 (tiny-N, memory-bound)
template <int BM, int BN, int WN, bool RELU, bool OUT_BF16>
__global__ __launch_bounds__(256) void gemm_ff(
    const unsigned short* __restrict__ A, const unsigned short* __restrict__ Bw,
    const float* __restrict__ bias, void* __restrict__ Cptr,
    int M, int N, int K) {
  constexpr int BK = 32;
  constexpr int PTA = BM / 64;
  constexpr int PTB = BN / 64;
  __shared__ short As[BM * BK];
  __shared__ short Bs[BN * BK];

  const int t = threadIdx.x;
  const int lane = t & 63;
  const int wid = t >> 6;
  const int wr = wid / WN;
  const int wc = wid % WN;
  const int bm = blockIdx.x;
  const int bn = blockIdx.y;

  f32x4 acc[4][4] = {};
  const unsigned short* Abase = A + (size_t)bm * BM * K;
  const unsigned short* Bbase = Bw + (size_t)bn * BN * K;
  const int kIters = K / BK;
  for (int kk = 0; kk < kIters; ++kk) {
    const int k0 = kk * BK;
#pragma unroll
    for (int r = 0; r < PTB; ++r) {
      const int s = r * 256 + t;
      gll16(Bbase + (size_t)(s >> 2) * K + k0 + (s & 3) * 8, &Bs[s * 8]);
    }
#pragma unroll
    for (int r = 0; r < PTA; ++r) {
      const int s = r * 256 + t;
      gll16(Abase + (size_t)(s >> 2) * K + k0 + (s & 3) * 8, &As[s * 8]);
    }
    __syncthreads();
    short8 af[4], bfg[4];
#pragma unroll
    for (int m = 0; m < 4; ++m)
      af[m] = *(const short8*)&As[(wr * 64 + m * 16 + (lane & 15)) * BK + ((lane >> 4) * 8)];
#pragma unroll
    for (int n = 0; n < 4; ++n)
      bfg[n] = *(const short8*)&Bs[(wc * 64 + n * 16 + (lane & 15)) * BK + ((lane >> 4) * 8)];
#pragma unroll
    for (int m = 0; m < 4; ++m)
#pragma unroll
      for (int n = 0; n < 4; ++n)
        acc[m][n] = __builtin_amdgcn_mfma_f32_16x16x32_bf16(af[m], bfg[n], acc[m][n], 0, 0, 0);
    __syncthreads();
  }

#pragma unroll
  for (int m = 0; m < 4; ++m) {
#pragma unroll
    for (int j = 0; j < 4; ++j) {
      const int rl = wr * 64 + m * 16 + ((lane >> 4) << 2) + j;
      const size_t row = (size_t)bm * BM + rl;
#pragma unroll
      for (int n = 0; n < 4; ++n) {
        const int col = bn * BN + wc * 64 + n * 16 + (lane & 15);
        float v = acc[m][n][j];
        v += bias[col];
        if constexpr (RELU) v = fmaxf(v, 0.f);
        if constexpr (OUT_BF16)
          ((unsigned short*)Cptr)[row * (size_t)N + col] = f2bf(v);
        else
          ((float*)Cptr)[row * (size_t)N + col] = v;
      }
    }
  }
}

extern "C" void kernel_launch(void* const* d_in, const int* in_sizes, int n_in,
                              void* d_out, int out_size, void* d_ws, size_t ws_size,
                              hipStream_t stream) {
  const float* states = (const float*)d_in[0];
  const float* W1 = (const float*)d_in[1];
  const float* b1 = (const float*)d_in[2];
  const float* W2 = (const float*)d_in[3];
  const float* b2 = (const float*)d_in[4];
  const float* Wq = (const float*)d_in[5];
  const float* bq = (const float*)d_in[6];
  float* out = (float*)d_out;

  const int D = 1024, H1 = 2048, H2 = 1024, AO = 64;
  const int B = in_sizes[0] / D;

  unsigned short* W1b = (unsigned short*)d_ws;  // [H1][D]
  unsigned short* W2b = W1b + (size_t)H1 * D;   // [H2][H1]
  unsigned short* Wqb = W2b + (size_t)H2 * H1;  // [AO][H2]
  char* dynbase = (char*)(Wqb + (size_t)AO * H2);

  const size_t wbytes = ((size_t)H1 * D + (size_t)H2 * H1 + (size_t)AO * H2) * 2;
  size_t avail = ws_size > wbytes ? ws_size - wbytes : 0;
  const size_t per_row = 4 + (size_t)(D + H1 + H2) * 2;
  long long bc = (long long)(avail / per_row);
  bc = (bc / 256) * 256;
  if (bc <= 0) bc = 256;
  if (bc > B) bc = B;

  float* scale1 = (float*)dynbase;
  unsigned short* sn = (unsigned short*)(scale1 + bc);
  unsigned short* h1 = sn + (size_t)bc * D;
  unsigned short* h2 = h1 + (size_t)bc * H1;

  cvt_w3<<<dim3(2048), dim3(256), 0, stream>>>(W1, W2, Wq, W1b, W2b, Wqb,
                                               H1 * D, H2 * H1, AO * H2);

  for (int off = 0; off < B; off += (int)bc) {
    const int cur = (B - off) < (int)bc ? (B - off) : (int)bc;
    norm_rows_f32<1024><<<dim3(cur / 4), dim3(256), 0, stream>>>(
        states + (size_t)off * D, sn, cur);
    // G1: h1 = relu(sn·W1^T + b1)
    gemm_sb<false, true, true>
        <<<dim3((cur / 128) * (H1 / 256)), dim3(512), 0, stream>>>(
            sn, W1b, b1, nullptr, h1, cur, H1, D);
    // scale1[row] = 1/(||h1 row||+eps)
    rownorm_bf16<2048><<<dim3(cur / 4), dim3(256), 0, stream>>>(h1, scale1, cur);
    // G2: h2 = relu(scale1·(h1·W2^T) + b2)
    gemm_sb<true, true, true>
        <<<dim3((cur / 128) * (H2 / 256)), dim3(512), 0, stream>>>(
            h1, W2b, b2, scale1, h2, cur, H2, H1);
    // G3: q = h2·Wq^T + bq
    gemm_ff<256, 64, 1, false, false>
        <<<dim3(cur / 256), dim3(256), 0, stream>>>(
            h2, Wqb, bq, out + (size_t)off * AO, cur, AO, H2);
  }
}

// Round 16
// 673.329 us; speedup vs baseline: 3.0159x; 3.0159x over previous
//
#include <hip/hip_runtime.h>
#include <stdint.h>

typedef __attribute__((ext_vector_type(8))) short short8;
typedef __attribute__((ext_vector_type(4))) short short4v;
typedef __attribute__((ext_vector_type(4))) float f32x4;

#define DEVINL __device__ __forceinline__

DEVINL unsigned short f2bf(float x) {
  uint32_t b = __float_as_uint(x);
  b += 0x7fffu + ((b >> 16) & 1u);
  return (unsigned short)(b >> 16);
}
DEVINL float bf2f(unsigned short u) {
  return __uint_as_float(((uint32_t)u) << 16);
}

DEVINL void gll16(const void* g, void* l) {
  __builtin_amdgcn_global_load_lds(
      (const __attribute__((address_space(1))) uint32_t*)g,
      (__attribute__((address_space(3))) uint32_t*)l, 16, 0, 0);
}

// one launch converts all three weight matrices to bf16
__global__ void cvt_w3(const float* __restrict__ W1, const float* __restrict__ W2,
                       const float* __restrict__ Wq, unsigned short* __restrict__ o1,
                       unsigned short* __restrict__ o2, unsigned short* __restrict__ oq,
                       int n1, int n2, int nq) {
  int i = blockIdx.x * blockDim.x + threadIdx.x;
  const int st = gridDim.x * blockDim.x;
  const int tot = n1 + n2 + nq;
  for (; i < tot; i += st) {
    if (i < n1)
      o1[i] = f2bf(W1[i]);
    else if (i < n1 + n2)
      o2[i - n1] = f2bf(W2[i - n1]);
    else
      oq[i - n1 - n2] = f2bf(Wq[i - n1 - n2]);
  }
}

// wave-per-row: out_row = bf16(in_row / (||in_row|| + eps))
template <int D>
__global__ __launch_bounds__(256) void norm_rows_f32(
    const float* __restrict__ in, unsigned short* __restrict__ out, int nrows) {
  const int lane = threadIdx.x & 63;
  const int row = blockIdx.x * 4 + (threadIdx.x >> 6);
  if (row >= nrows) return;
  const float* r = in + (size_t)row * D;
  constexpr int NSEG = D / 256;
  f32x4 v[NSEG];
  float ssq = 0.f;
#pragma unroll
  for (int i = 0; i < NSEG; ++i) {
    v[i] = *(const f32x4*)(r + (i * 64 + lane) * 4);
#pragma unroll
    for (int j = 0; j < 4; ++j) ssq += v[i][j] * v[i][j];
  }
#pragma unroll
  for (int m = 32; m >= 1; m >>= 1) ssq += __shfl_xor(ssq, m, 64);
  const float sc = 1.0f / (sqrtf(ssq) + 1e-8f);
  unsigned short* o = out + (size_t)row * D;
#pragma unroll
  for (int i = 0; i < NSEG; ++i) {
    short4v u;
#pragma unroll
    for (int j = 0; j < 4; ++j) u[j] = (short)f2bf(v[i][j] * sc);
    *(short4v*)(o + (i * 64 + lane) * 4) = u;
  }
}

// wave-per-row: scale[row] = 1/(||bf16 row|| + eps)
template <int H>
__global__ __launch_bounds__(256) void rownorm_bf16(
    const unsigned short* __restrict__ in, float* __restrict__ scale, int nrows) {
  const int lane = threadIdx.x & 63;
  const int row = blockIdx.x * 4 + (threadIdx.x >> 6);
  if (row >= nrows) return;
  const unsigned short* r = in + (size_t)row * H;
  constexpr int NSEG = H / 512;
  float ssq = 0.f;
#pragma unroll
  for (int i = 0; i < NSEG; ++i) {
    short8 u = *(const short8*)(r + (i * 64 + lane) * 8);
#pragma unroll
    for (int j = 0; j < 8; ++j) {
      float f = bf2f((unsigned short)u[j]);
      ssq += f * f;
    }
  }
#pragma unroll
  for (int m = 32; m >= 1; m >>= 1) ssq += __shfl_xor(ssq, m, 64);
  if (lane == 0) scale[row] = 1.0f / (sqrtf(ssq) + 1e-8f);
}

// 256x256 counted-vmcnt 4-phase GEMM — r10-validated (PASS, 673 us total).
// BK=64, 8 waves (2Mx4N), per-wave C = 128x64 (acc 8x4). Dbuf LDS 128 KiB.
// CONSUMPTION map (per wave): PH0/PH1 read dB0..dB3 + dA0 (wr=0) / dA2
// (wr=1); PH2/PH3 read dA1 (wr=0) / dA3 (wr=1).
// Issue order of tile t+1's 8 gll16 (2/phase):
//   PH0: B0,B1 | PH1: B2,B3 | PH2: A0,A2 | PH3: A1,A3
// Waits (counted, NEVER 0 in loop):
//   PH1-end vmcnt(4): drains A1,A3(t) -> PH2/PH3 reads of dA1/dA3(cur) safe.
//   PH3-end vmcnt(2): drains all but A1,A3(t+1) -> next PH0/PH1 reads safe.
// Prologue B0..B3,A0,A2,A1,A3 + vmcnt(2) leaves exactly A1,A3 in flight.
// Cross-wave publish: every wave stages copies of every region and drains
// its OWN loads before each barrier (r5/r10-validated argument).
// T2 involution swizzle (128B rows): stored 16B-unit at pos p of row r is
// global unit p^(r&7) (pre-swizzled source; LDS linear for gll16); ds_read
// pos u^(r&7), r&7==lane&7 -> 0 conflicts measured. T5 setprio per cluster.
template <bool SCALE, bool RELU, bool OUT_BF16>
__global__ __launch_bounds__(512, 1) void gemm_p8(
    const unsigned short* __restrict__ A, const unsigned short* __restrict__ Bw,
    const float* __restrict__ bias, const float* __restrict__ scaleArr,
    void* __restrict__ Cptr, int M, int N, int K) {
  extern __shared__ __align__(16) short lds[];  // 2 x (A[256][64] | B[256][64])

  const int t = threadIdx.x;
  const int lane = t & 63;
  const int wid = t >> 6;   // 0..7
  const int wr = wid >> 2;  // 0..1  (128-row half)
  const int wc = wid & 3;   // 0..3  (64-col quarter)

  const int nwg = gridDim.x;
  const int bid = blockIdx.x;
  int wg = bid;
  if ((nwg & 7) == 0) wg = (bid & 7) * (nwg >> 3) + (bid >> 3);
  const int numBN = N >> 8;
  const int bm = wg / numBN;
  const int bn = wg % numBN;

  // Staging: thread t covers row (t>>3)+j*64 (j=0..3), 16B-unit pos t&7.
  // Pre-swizzled source: global unit = (t&7) ^ (row&7); row&7 == (t>>3)&7.
  const int row0 = t >> 3;
  const int usrc = ((t & 7) ^ (row0 & 7)) << 3;
  const unsigned short* sA0 = A + (size_t)(bm * 256 + row0) * K + usrc;
  const unsigned short* sA1 = A + (size_t)(bm * 256 + 64 + row0) * K + usrc;
  const unsigned short* sA2 = A + (size_t)(bm * 256 + 128 + row0) * K + usrc;
  const unsigned short* sA3 = A + (size_t)(bm * 256 + 192 + row0) * K + usrc;
  const unsigned short* sB0 = Bw + (size_t)(bn * 256 + row0) * K + usrc;
  const unsigned short* sB1 = Bw + (size_t)(bn * 256 + 64 + row0) * K + usrc;
  const unsigned short* sB2 = Bw + (size_t)(bn * 256 + 128 + row0) * K + usrc;
  const unsigned short* sB3 = Bw + (size_t)(bn * 256 + 192 + row0) * K + usrc;
  const int dA0 = t * 8, dA1 = 4096 + t * 8, dA2 = 8192 + t * 8, dA3 = 12288 + t * 8;
  const int dB0 = 16384 + t * 8, dB1 = 20480 + t * 8, dB2 = 24576 + t * 8, dB3 = 28672 + t * 8;

  // ds_read: row r, global unit u = kh*4+(lane>>4) -> pos u^(r&7); r&7==lane&7.
  const int sw = lane & 7;
  const int pA = (wr * 128 + (lane & 15)) * 64;
  const int pB = 16384 + (wc * 64 + (lane & 15)) * 64;
  const int pu0 = (((lane >> 4)) ^ sw) * 8;
  const int pu1 = ((4 | (lane >> 4)) ^ sw) * 8;

  f32x4 acc[8][4] = {};
  const int nt = K >> 6;

  // prologue: stage tile 0; A1,A3 LAST so vmcnt(2) leaves exactly them in flight
  gll16(sB0, &lds[dB0]);
  gll16(sB1, &lds[dB1]);
  gll16(sB2, &lds[dB2]);
  gll16(sB3, &lds[dB3]);
  gll16(sA0, &lds[dA0]);
  gll16(sA2, &lds[dA2]);
  gll16(sA1, &lds[dA1]);
  gll16(sA3, &lds[dA3]);
  asm volatile("s_waitcnt vmcnt(2)" ::: "memory");
  asm volatile("s_barrier" ::: "memory");

  for (int tt = 0; tt < nt; ++tt) {
    const int cb = (tt & 1) << 15;  // current buf (shorts)
    const int nb = cb ^ 32768;
    int kf = tt + 1;
    if (kf == nt) kf = 0;  // wrap-stage (unused, keeps vmcnt uniform)
    const int kn = kf * 64;
    short8 b0_[4], b1_[4];
    // ---------- PH0: (mh=0, kh=0); issue B0,B1(t+1) ----------
    {
      const short8 a0 = *(const short8*)&lds[cb + pA + 0 * 1024 + pu0];
      const short8 a1 = *(const short8*)&lds[cb + pA + 1 * 1024 + pu0];
      const short8 a2 = *(const short8*)&lds[cb + pA + 2 * 1024 + pu0];
      const short8 a3 = *(const short8*)&lds[cb + pA + 3 * 1024 + pu0];
#pragma unroll
      for (int n = 0; n < 4; ++n)
        b0_[n] = *(const short8*)&lds[cb + pB + n * 1024 + pu0];
      gll16(sB0 + kn, &lds[nb + dB0]);
      gll16(sB1 + kn, &lds[nb + dB1]);
      asm volatile("s_barrier" ::: "memory");
      asm volatile("s_waitcnt lgkmcnt(0)" ::: "memory");
      __builtin_amdgcn_sched_barrier(0);
      __builtin_amdgcn_s_setprio(1);
#pragma unroll
      for (int n = 0; n < 4; ++n) {
        acc[0][n] = __builtin_amdgcn_mfma_f32_16x16x32_bf16(a0, b0_[n], acc[0][n], 0, 0, 0);
        acc[1][n] = __builtin_amdgcn_mfma_f32_16x16x32_bf16(a1, b0_[n], acc[1][n], 0, 0, 0);
        acc[2][n] = __builtin_amdgcn_mfma_f32_16x16x32_bf16(a2, b0_[n], acc[2][n], 0, 0, 0);
        acc[3][n] = __builtin_amdgcn_mfma_f32_16x16x32_bf16(a3, b0_[n], acc[3][n], 0, 0, 0);
      }
      __builtin_amdgcn_s_setprio(0);
      asm volatile("s_barrier" ::: "memory");
    }
    // ---------- PH1: (mh=0, kh=1); issue B2,B3(t+1); vmcnt(4) ----------
    {
      const short8 a0 = *(const short8*)&lds[cb + pA + 0 * 1024 + pu1];
      const short8 a1 = *(const short8*)&lds[cb + pA + 1 * 1024 + pu1];
      const short8 a2 = *(const short8*)&lds[cb + pA + 2 * 1024 + pu1];
      const short8 a3 = *(const short8*)&lds[cb + pA + 3 * 1024 + pu1];
#pragma unroll
      for (int n = 0; n < 4; ++n)
        b1_[n] = *(const short8*)&lds[cb + pB + n * 1024 + pu1];
      gll16(sB2 + kn, &lds[nb + dB2]);
      gll16(sB3 + kn, &lds[nb + dB3]);
      asm volatile("s_barrier" ::: "memory");
      asm volatile("s_waitcnt lgkmcnt(0)" ::: "memory");
      __builtin_amdgcn_sched_barrier(0);
      __builtin_amdgcn_s_setprio(1);
#pragma unroll
      for (int n = 0; n < 4; ++n) {
        acc[0][n] = __builtin_amdgcn_mfma_f32_16x16x32_bf16(a0, b1_[n], acc[0][n], 0, 0, 0);
        acc[1][n] = __builtin_amdgcn_mfma_f32_16x16x32_bf16(a1, b1_[n], acc[1][n], 0, 0, 0);
        acc[2][n] = __builtin_amdgcn_mfma_f32_16x16x32_bf16(a2, b1_[n], acc[2][n], 0, 0, 0);
        acc[3][n] = __builtin_amdgcn_mfma_f32_16x16x32_bf16(a3, b1_[n], acc[3][n], 0, 0, 0);
      }
      __builtin_amdgcn_s_setprio(0);
      asm volatile("s_waitcnt vmcnt(4)" ::: "memory");  // drain A1,A3(t)
      asm volatile("s_barrier" ::: "memory");
    }
    // ---------- PH2: (mh=1, kh=0); issue A0,A2(t+1) ----------
    {
      const short8 a0 = *(const short8*)&lds[cb + pA + 4 * 1024 + pu0];
      const short8 a1 = *(const short8*)&lds[cb + pA + 5 * 1024 + pu0];
      const short8 a2 = *(const short8*)&lds[cb + pA + 6 * 1024 + pu0];
      const short8 a3 = *(const short8*)&lds[cb + pA + 7 * 1024 + pu0];
      gll16(sA0 + kn, &lds[nb + dA0]);
      gll16(sA2 + kn, &lds[nb + dA2]);
      asm volatile("s_barrier" ::: "memory");
      asm volatile("s_waitcnt lgkmcnt(0)" ::: "memory");
      __builtin_amdgcn_sched_barrier(0);
      __builtin_amdgcn_s_setprio(1);
#pragma unroll
      for (int n = 0; n < 4; ++n) {
        acc[4][n] = __builtin_amdgcn_mfma_f32_16x16x32_bf16(a0, b0_[n], acc[4][n], 0, 0, 0);
        acc[5][n] = __builtin_amdgcn_mfma_f32_16x16x32_bf16(a1, b0_[n], acc[5][n], 0, 0, 0);
        acc[6][n] = __builtin_amdgcn_mfma_f32_16x16x32_bf16(a2, b0_[n], acc[6][n], 0, 0, 0);
        acc[7][n] = __builtin_amdgcn_mfma_f32_16x16x32_bf16(a3, b0_[n], acc[7][n], 0, 0, 0);
      }
      __builtin_amdgcn_s_setprio(0);
      asm volatile("s_barrier" ::: "memory");
    }
    // ---------- PH3: (mh=1, kh=1); issue A1,A3(t+1); vmcnt(2) ----------
    {
      const short8 a0 = *(const short8*)&lds[cb + pA + 4 * 1024 + pu1];
      const short8 a1 = *(const short8*)&lds[cb + pA + 5 * 1024 + pu1];
      const short8 a2 = *(const short8*)&lds[cb + pA + 6 * 1024 + pu1];
      const short8 a3 = *(const short8*)&lds[cb + pA + 7 * 1024 + pu1];
      gll16(sA1 + kn, &lds[nb + dA1]);
      gll16(sA3 + kn, &lds[nb + dA3]);
      asm volatile("s_barrier" ::: "memory");
      asm volatile("s_waitcnt lgkmcnt(0)" ::: "memory");
      __builtin_amdgcn_sched_barrier(0);
      __builtin_amdgcn_s_setprio(1);
#pragma unroll
      for (int n = 0; n < 4; ++n) {
        acc[4][n] = __builtin_amdgcn_mfma_f32_16x16x32_bf16(a0, b1_[n], acc[4][n], 0, 0, 0);
        acc[5][n] = __builtin_amdgcn_mfma_f32_16x16x32_bf16(a1, b1_[n], acc[5][n], 0, 0, 0);
        acc[6][n] = __builtin_amdgcn_mfma_f32_16x16x32_bf16(a2, b1_[n], acc[6][n], 0, 0, 0);
        acc[7][n] = __builtin_amdgcn_mfma_f32_16x16x32_bf16(a3, b1_[n], acc[7][n], 0, 0, 0);
      }
      __builtin_amdgcn_s_setprio(0);
      asm volatile("s_waitcnt vmcnt(2)" ::: "memory");  // drain B*(t+1), A0,A2(t+1)
      asm volatile("s_barrier" ::: "memory");
    }
  }
  asm volatile("s_waitcnt vmcnt(0)" ::: "memory");  // drain wrap-stage

  // epilogue: frag row=(lane>>4)*4+j, col=lane&15
#pragma unroll
  for (int m = 0; m < 8; ++m) {
#pragma unroll
    for (int j = 0; j < 4; ++j) {
      const int rl = wr * 128 + m * 16 + ((lane >> 4) << 2) + j;
      const size_t row = (size_t)bm * 256 + rl;
      float sc = 1.0f;
      if constexpr (SCALE) sc = scaleArr[row];
#pragma unroll
      for (int n = 0; n < 4; ++n) {
        const int col = bn * 256 + wc * 64 + n * 16 + (lane & 15);
        float x = acc[m][n][j];
        if constexpr (SCALE) x *= sc;
        x += bias[col];
        if constexpr (RELU) x = fmaxf(x, 0.f);
        if constexpr (OUT_BF16)
          ((unsigned short*)Cptr)[row * (size_t)N + col] = f2bf(x);
        else
          ((float*)Cptr)[row * (size_t)N + col] = x;
      }
    }
  }
}

// 2-phase GEMM for G3 (tiny-N, memory-bound)
template <int BM, int BN, int WN, bool RELU, bool OUT_BF16>
__global__ __launch_bounds__(256) void gemm_ff(
    const unsigned short* __restrict__ A, const unsigned short* __restrict__ Bw,
    const float* __restrict__ bias, void* __restrict__ Cptr,
    int M, int N, int K) {
  constexpr int BK = 32;
  constexpr int PTA = BM / 64;
  constexpr int PTB = BN / 64;
  __shared__ short As[BM * BK];
  __shared__ short Bs[BN * BK];

  const int t = threadIdx.x;
  const int lane = t & 63;
  const int wid = t >> 6;
  const int wr = wid / WN;
  const int wc = wid % WN;
  const int bm = blockIdx.x;
  const int bn = blockIdx.y;

  f32x4 acc[4][4] = {};
  const unsigned short* Abase = A + (size_t)bm * BM * K;
  const unsigned short* Bbase = Bw + (size_t)bn * BN * K;
  const int kIters = K / BK;
  for (int kk = 0; kk < kIters; ++kk) {
    const int k0 = kk * BK;
#pragma unroll
    for (int r = 0; r < PTB; ++r) {
      const int s = r * 256 + t;
      gll16(Bbase + (size_t)(s >> 2) * K + k0 + (s & 3) * 8, &Bs[s * 8]);
    }
#pragma unroll
    for (int r = 0; r < PTA; ++r) {
      const int s = r * 256 + t;
      gll16(Abase + (size_t)(s >> 2) * K + k0 + (s & 3) * 8, &As[s * 8]);
    }
    __syncthreads();
    short8 af[4], bfg[4];
#pragma unroll
    for (int m = 0; m < 4; ++m)
      af[m] = *(const short8*)&As[(wr * 64 + m * 16 + (lane & 15)) * BK + ((lane >> 4) * 8)];
#pragma unroll
    for (int n = 0; n < 4; ++n)
      bfg[n] = *(const short8*)&Bs[(wc * 64 + n * 16 + (lane & 15)) * BK + ((lane >> 4) * 8)];
#pragma unroll
    for (int m = 0; m < 4; ++m)
#pragma unroll
      for (int n = 0; n < 4; ++n)
        acc[m][n] = __builtin_amdgcn_mfma_f32_16x16x32_bf16(af[m], bfg[n], acc[m][n], 0, 0, 0);
    __syncthreads();
  }

#pragma unroll
  for (int m = 0; m < 4; ++m) {
#pragma unroll
    for (int j = 0; j < 4; ++j) {
      const int rl = wr * 64 + m * 16 + ((lane >> 4) << 2) + j;
      const size_t row = (size_t)bm * BM + rl;
#pragma unroll
      for (int n = 0; n < 4; ++n) {
        const int col = bn * BN + wc * 64 + n * 16 + (lane & 15);
        float v = acc[m][n][j];
        v += bias[col];
        if constexpr (RELU) v = fmaxf(v, 0.f);
        if constexpr (OUT_BF16)
          ((unsigned short*)Cptr)[row * (size_t)N + col] = f2bf(v);
        else
          ((float*)Cptr)[row * (size_t)N + col] = v;
      }
    }
  }
}

extern "C" void kernel_launch(void* const* d_in, const int* in_sizes, int n_in,
                              void* d_out, int out_size, void* d_ws, size_t ws_size,
                              hipStream_t stream) {
  const float* states = (const float*)d_in[0];
  const float* W1 = (const float*)d_in[1];
  const float* b1 = (const float*)d_in[2];
  const float* W2 = (const float*)d_in[3];
  const float* b2 = (const float*)d_in[4];
  const float* Wq = (const float*)d_in[5];
  const float* bq = (const float*)d_in[6];
  float* out = (float*)d_out;

  const int D = 1024, H1 = 2048, H2 = 1024, AO = 64;
  const int B = in_sizes[0] / D;

  unsigned short* W1b = (unsigned short*)d_ws;  // [H1][D]
  unsigned short* W2b = W1b + (size_t)H1 * D;   // [H2][H1]
  unsigned short* Wqb = W2b + (size_t)H2 * H1;  // [AO][H2]
  char* dynbase = (char*)(Wqb + (size_t)AO * H2);

  const size_t wbytes = ((size_t)H1 * D + (size_t)H2 * H1 + (size_t)AO * H2) * 2;
  size_t avail = ws_size > wbytes ? ws_size - wbytes : 0;
  const size_t per_row = 4 + (size_t)(D + H1 + H2) * 2;
  long long bc = (long long)(avail / per_row);
  bc = (bc / 256) * 256;
  if (bc <= 0) bc = 256;
  if (bc > B) bc = B;

  float* scale1 = (float*)dynbase;
  unsigned short* sn = (unsigned short*)(scale1 + bc);
  unsigned short* h1 = sn + (size_t)bc * D;
  unsigned short* h2 = h1 + (size_t)bc * H1;

  // allow 128 KiB dynamic LDS (host-side attribute set; capture-safe)
  (void)hipFuncSetAttribute((const void*)gemm_p8<false, true, true>,
                            hipFuncAttributeMaxDynamicSharedMemorySize, 131072);
  (void)hipFuncSetAttribute((const void*)gemm_p8<true, true, true>,
                            hipFuncAttributeMaxDynamicSharedMemorySize, 131072);

  cvt_w3<<<dim3(2048), dim3(256), 0, stream>>>(W1, W2, Wq, W1b, W2b, Wqb,
                                               H1 * D, H2 * H1, AO * H2);

  for (int off = 0; off < B; off += (int)bc) {
    const int cur = (B - off) < (int)bc ? (B - off) : (int)bc;
    norm_rows_f32<1024><<<dim3(cur / 4), dim3(256), 0, stream>>>(
        states + (size_t)off * D, sn, cur);
    // G1: h1 = relu(sn·W1^T + b1)
    gemm_p8<false, true, true>
        <<<dim3((cur / 256) * (H1 / 256)), dim3(512), 131072, stream>>>(
            sn, W1b, b1, nullptr, h1, cur, H1, D);
    // scale1[row] = 1/(||h1 row||+eps)
    rownorm_bf16<2048><<<dim3(cur / 4), dim3(256), 0, stream>>>(h1, scale1, cur);
    // G2: h2 = relu(scale1·(h1·W2^T) + b2)
    gemm_p8<true, true, true>
        <<<dim3((cur / 256) * (H2 / 256)), dim3(512), 131072, stream>>>(
            h1, W2b, b2, scale1, h2, cur, H2, H1);
    // G3: q = h2·Wq^T + bq
    gemm_ff<256, 64, 1, false, false>
        <<<dim3(cur / 256), dim3(256), 0, stream>>>(
            h2, Wqb, bq, out + (size_t)off * AO, cur, AO, H2);
  }
}

// Round 17
// 655.904 us; speedup vs baseline: 3.0960x; 1.0266x over previous
//
#include <hip/hip_runtime.h>
#include <stdint.h>

typedef __attribute__((ext_vector_type(8))) short short8;
typedef __attribute__((ext_vector_type(4))) short short4v;
typedef __attribute__((ext_vector_type(4))) float f32x4;

#define DEVINL __device__ __forceinline__

DEVINL unsigned short f2bf(float x) {
  uint32_t b = __float_as_uint(x);
  b += 0x7fffu + ((b >> 16) & 1u);
  return (unsigned short)(b >> 16);
}
DEVINL float bf2f(unsigned short u) {
  return __uint_as_float(((uint32_t)u) << 16);
}

DEVINL void gll16(const void* g, void* l) {
  __builtin_amdgcn_global_load_lds(
      (const __attribute__((address_space(1))) uint32_t*)g,
      (__attribute__((address_space(3))) uint32_t*)l, 16, 0, 0);
}

// one launch converts all three weight matrices to bf16
__global__ void cvt_w3(const float* __restrict__ W1, const float* __restrict__ W2,
                       const float* __restrict__ Wq, unsigned short* __restrict__ o1,
                       unsigned short* __restrict__ o2, unsigned short* __restrict__ oq,
                       int n1, int n2, int nq) {
  int i = blockIdx.x * blockDim.x + threadIdx.x;
  const int st = gridDim.x * blockDim.x;
  const int tot = n1 + n2 + nq;
  for (; i < tot; i += st) {
    if (i < n1)
      o1[i] = f2bf(W1[i]);
    else if (i < n1 + n2)
      o2[i - n1] = f2bf(W2[i - n1]);
    else
      oq[i - n1 - n2] = f2bf(Wq[i - n1 - n2]);
  }
}

// wave-per-row: out_row = bf16(in_row / (||in_row|| + eps))
template <int D>
__global__ __launch_bounds__(256) void norm_rows_f32(
    const float* __restrict__ in, unsigned short* __restrict__ out, int nrows) {
  const int lane = threadIdx.x & 63;
  const int row = blockIdx.x * 4 + (threadIdx.x >> 6);
  if (row >= nrows) return;
  const float* r = in + (size_t)row * D;
  constexpr int NSEG = D / 256;
  f32x4 v[NSEG];
  float ssq = 0.f;
#pragma unroll
  for (int i = 0; i < NSEG; ++i) {
    v[i] = *(const f32x4*)(r + (i * 64 + lane) * 4);
#pragma unroll
    for (int j = 0; j < 4; ++j) ssq += v[i][j] * v[i][j];
  }
#pragma unroll
  for (int m = 32; m >= 1; m >>= 1) ssq += __shfl_xor(ssq, m, 64);
  const float sc = 1.0f / (sqrtf(ssq) + 1e-8f);
  unsigned short* o = out + (size_t)row * D;
#pragma unroll
  for (int i = 0; i < NSEG; ++i) {
    short4v u;
#pragma unroll
    for (int j = 0; j < 4; ++j) u[j] = (short)f2bf(v[i][j] * sc);
    *(short4v*)(o + (i * 64 + lane) * 4) = u;
  }
}

// scale[row] = 1/(sqrt(sum of np partials)+eps)
__global__ __launch_bounds__(256) void reduce_scale(
    const float* __restrict__ part, float* __restrict__ scale, int nrows, int np) {
  const int row = blockIdx.x * blockDim.x + threadIdx.x;
  if (row >= nrows) return;
  const float* p = part + (size_t)row * np;
  float s = 0.f;
  for (int i = 0; i < np; i += 4) {
    f32x4 v = *(const f32x4*)(p + i);
    s += v[0] + v[1] + v[2] + v[3];
  }
  scale[row] = 1.0f / (sqrtf(s) + 1e-8f);
}

// 256x256 counted-vmcnt 4-phase GEMM — r10/r16-validated ledger (PASS x3,
// 673 us total). BK=64, 8 waves (2Mx4N), per-wave C = 128x64 (acc 8x4).
// Dbuf LDS 128 KiB.
// CONSUMPTION map (per wave): PH0/PH1 read dB0..dB3 + dA0 (wr=0) / dA2
// (wr=1); PH2/PH3 read dA1 (wr=0) / dA3 (wr=1).
// Issue order of tile t+1's 8 gll16 (2/phase):
//   PH0: B0,B1 | PH1: B2,B3 | PH2: A0,A2 | PH3: A1,A3
// Waits (counted, NEVER 0 in loop):
//   PH1-end vmcnt(4): drains A1,A3(t) -> PH2/PH3 reads of dA1/dA3(cur) safe.
//   PH3-end vmcnt(2): drains all but A1,A3(t+1) -> next PH0/PH1 reads safe.
// Prologue B0..B3,A0,A2,A1,A3 + vmcnt(2) leaves exactly A1,A3 in flight.
// r17 change: sched_barrier(0) REMOVED (m141: order-pinning defeats the
// scheduler; m201 template has none). Manual lgkmcnt(0) kept as in the
// m201 template; operand deps are plain loads -> compiler-tracked, so
// correctness is unaffected.
// T2 involution swizzle (128B rows): stored 16B-unit at pos p of row r is
// global unit p^(r&7); ds_read pos u^(r&7), r&7==lane&7 -> 0 conflicts.
// ACC_PART (G1): epilogue writes per-(row, bn, wc) partial ssq of the
// post-relu outputs to aux[row*(numBN*4) + bn*4 + wc] — each slot written
// exactly once (no atomics, deterministic). SCALE (G2): multiply row by
// aux[row] before bias.
template <bool ACC_PART, bool SCALE, bool RELU, bool OUT_BF16>
__global__ __launch_bounds__(512, 1) void gemm_p8(
    const unsigned short* __restrict__ A, const unsigned short* __restrict__ Bw,
    const float* __restrict__ bias, float* __restrict__ aux,
    void* __restrict__ Cptr, int M, int N, int K) {
  extern __shared__ __align__(16) short lds[];  // 2 x (A[256][64] | B[256][64])

  const int t = threadIdx.x;
  const int lane = t & 63;
  const int wid = t >> 6;   // 0..7
  const int wr = wid >> 2;  // 0..1  (128-row half)
  const int wc = wid & 3;   // 0..3  (64-col quarter)

  const int nwg = gridDim.x;
  const int bid = blockIdx.x;
  int wg = bid;
  if ((nwg & 7) == 0) wg = (bid & 7) * (nwg >> 3) + (bid >> 3);
  const int numBN = N >> 8;
  const int bm = wg / numBN;
  const int bn = wg % numBN;

  // Staging: thread t covers row (t>>3)+j*64 (j=0..3), 16B-unit pos t&7.
  // Pre-swizzled source: global unit = (t&7) ^ (row&7); row&7 == (t>>3)&7.
  const int row0 = t >> 3;
  const int usrc = ((t & 7) ^ (row0 & 7)) << 3;
  const unsigned short* sA0 = A + (size_t)(bm * 256 + row0) * K + usrc;
  const unsigned short* sA1 = A + (size_t)(bm * 256 + 64 + row0) * K + usrc;
  const unsigned short* sA2 = A + (size_t)(bm * 256 + 128 + row0) * K + usrc;
  const unsigned short* sA3 = A + (size_t)(bm * 256 + 192 + row0) * K + usrc;
  const unsigned short* sB0 = Bw + (size_t)(bn * 256 + row0) * K + usrc;
  const unsigned short* sB1 = Bw + (size_t)(bn * 256 + 64 + row0) * K + usrc;
  const unsigned short* sB2 = Bw + (size_t)(bn * 256 + 128 + row0) * K + usrc;
  const unsigned short* sB3 = Bw + (size_t)(bn * 256 + 192 + row0) * K + usrc;
  const int dA0 = t * 8, dA1 = 4096 + t * 8, dA2 = 8192 + t * 8, dA3 = 12288 + t * 8;
  const int dB0 = 16384 + t * 8, dB1 = 20480 + t * 8, dB2 = 24576 + t * 8, dB3 = 28672 + t * 8;

  // ds_read: row r, global unit u = kh*4+(lane>>4) -> pos u^(r&7); r&7==lane&7.
  const int sw = lane & 7;
  const int pA = (wr * 128 + (lane & 15)) * 64;
  const int pB = 16384 + (wc * 64 + (lane & 15)) * 64;
  const int pu0 = (((lane >> 4)) ^ sw) * 8;
  const int pu1 = ((4 | (lane >> 4)) ^ sw) * 8;

  f32x4 acc[8][4] = {};
  const int nt = K >> 6;

  // prologue: stage tile 0; A1,A3 LAST so vmcnt(2) leaves exactly them in flight
  gll16(sB0, &lds[dB0]);
  gll16(sB1, &lds[dB1]);
  gll16(sB2, &lds[dB2]);
  gll16(sB3, &lds[dB3]);
  gll16(sA0, &lds[dA0]);
  gll16(sA2, &lds[dA2]);
  gll16(sA1, &lds[dA1]);
  gll16(sA3, &lds[dA3]);
  asm volatile("s_waitcnt vmcnt(2)" ::: "memory");
  asm volatile("s_barrier" ::: "memory");

  for (int tt = 0; tt < nt; ++tt) {
    const int cb = (tt & 1) << 15;  // current buf (shorts)
    const int nb = cb ^ 32768;
    int kf = tt + 1;
    if (kf == nt) kf = 0;  // wrap-stage (unused, keeps vmcnt uniform)
    const int kn = kf * 64;
    short8 b0_[4], b1_[4];
    // ---------- PH0: (mh=0, kh=0); issue B0,B1(t+1) ----------
    {
      const short8 a0 = *(const short8*)&lds[cb + pA + 0 * 1024 + pu0];
      const short8 a1 = *(const short8*)&lds[cb + pA + 1 * 1024 + pu0];
      const short8 a2 = *(const short8*)&lds[cb + pA + 2 * 1024 + pu0];
      const short8 a3 = *(const short8*)&lds[cb + pA + 3 * 1024 + pu0];
#pragma unroll
      for (int n = 0; n < 4; ++n)
        b0_[n] = *(const short8*)&lds[cb + pB + n * 1024 + pu0];
      gll16(sB0 + kn, &lds[nb + dB0]);
      gll16(sB1 + kn, &lds[nb + dB1]);
      asm volatile("s_barrier" ::: "memory");
      asm volatile("s_waitcnt lgkmcnt(0)" ::: "memory");
      __builtin_amdgcn_s_setprio(1);
#pragma unroll
      for (int n = 0; n < 4; ++n) {
        acc[0][n] = __builtin_amdgcn_mfma_f32_16x16x32_bf16(a0, b0_[n], acc[0][n], 0, 0, 0);
        acc[1][n] = __builtin_amdgcn_mfma_f32_16x16x32_bf16(a1, b0_[n], acc[1][n], 0, 0, 0);
        acc[2][n] = __builtin_amdgcn_mfma_f32_16x16x32_bf16(a2, b0_[n], acc[2][n], 0, 0, 0);
        acc[3][n] = __builtin_amdgcn_mfma_f32_16x16x32_bf16(a3, b0_[n], acc[3][n], 0, 0, 0);
      }
      __builtin_amdgcn_s_setprio(0);
      asm volatile("s_barrier" ::: "memory");
    }
    // ---------- PH1: (mh=0, kh=1); issue B2,B3(t+1); vmcnt(4) ----------
    {
      const short8 a0 = *(const short8*)&lds[cb + pA + 0 * 1024 + pu1];
      const short8 a1 = *(const short8*)&lds[cb + pA + 1 * 1024 + pu1];
      const short8 a2 = *(const short8*)&lds[cb + pA + 2 * 1024 + pu1];
      const short8 a3 = *(const short8*)&lds[cb + pA + 3 * 1024 + pu1];
#pragma unroll
      for (int n = 0; n < 4; ++n)
        b1_[n] = *(const short8*)&lds[cb + pB + n * 1024 + pu1];
      gll16(sB2 + kn, &lds[nb + dB2]);
      gll16(sB3 + kn, &lds[nb + dB3]);
      asm volatile("s_barrier" ::: "memory");
      asm volatile("s_waitcnt lgkmcnt(0)" ::: "memory");
      __builtin_amdgcn_s_setprio(1);
#pragma unroll
      for (int n = 0; n < 4; ++n) {
        acc[0][n] = __builtin_amdgcn_mfma_f32_16x16x32_bf16(a0, b1_[n], acc[0][n], 0, 0, 0);
        acc[1][n] = __builtin_amdgcn_mfma_f32_16x16x32_bf16(a1, b1_[n], acc[1][n], 0, 0, 0);
        acc[2][n] = __builtin_amdgcn_mfma_f32_16x16x32_bf16(a2, b1_[n], acc[2][n], 0, 0, 0);
        acc[3][n] = __builtin_amdgcn_mfma_f32_16x16x32_bf16(a3, b1_[n], acc[3][n], 0, 0, 0);
      }
      __builtin_amdgcn_s_setprio(0);
      asm volatile("s_waitcnt vmcnt(4)" ::: "memory");  // drain A1,A3(t)
      asm volatile("s_barrier" ::: "memory");
    }
    // ---------- PH2: (mh=1, kh=0); issue A0,A2(t+1) ----------
    {
      const short8 a0 = *(const short8*)&lds[cb + pA + 4 * 1024 + pu0];
      const short8 a1 = *(const short8*)&lds[cb + pA + 5 * 1024 + pu0];
      const short8 a2 = *(const short8*)&lds[cb + pA + 6 * 1024 + pu0];
      const short8 a3 = *(const short8*)&lds[cb + pA + 7 * 1024 + pu0];
      gll16(sA0 + kn, &lds[nb + dA0]);
      gll16(sA2 + kn, &lds[nb + dA2]);
      asm volatile("s_barrier" ::: "memory");
      asm volatile("s_waitcnt lgkmcnt(0)" ::: "memory");
      __builtin_amdgcn_s_setprio(1);
#pragma unroll
      for (int n = 0; n < 4; ++n) {
        acc[4][n] = __builtin_amdgcn_mfma_f32_16x16x32_bf16(a0, b0_[n], acc[4][n], 0, 0, 0);
        acc[5][n] = __builtin_amdgcn_mfma_f32_16x16x32_bf16(a1, b0_[n], acc[5][n], 0, 0, 0);
        acc[6][n] = __builtin_amdgcn_mfma_f32_16x16x32_bf16(a2, b0_[n], acc[6][n], 0, 0, 0);
        acc[7][n] = __builtin_amdgcn_mfma_f32_16x16x32_bf16(a3, b0_[n], acc[7][n], 0, 0, 0);
      }
      __builtin_amdgcn_s_setprio(0);
      asm volatile("s_barrier" ::: "memory");
    }
    // ---------- PH3: (mh=1, kh=1); issue A1,A3(t+1); vmcnt(2) ----------
    {
      const short8 a0 = *(const short8*)&lds[cb + pA + 4 * 1024 + pu1];
      const short8 a1 = *(const short8*)&lds[cb + pA + 5 * 1024 + pu1];
      const short8 a2 = *(const short8*)&lds[cb + pA + 6 * 1024 + pu1];
      const short8 a3 = *(const short8*)&lds[cb + pA + 7 * 1024 + pu1];
      gll16(sA1 + kn, &lds[nb + dA1]);
      gll16(sA3 + kn, &lds[nb + dA3]);
      asm volatile("s_barrier" ::: "memory");
      asm volatile("s_waitcnt lgkmcnt(0)" ::: "memory");
      __builtin_amdgcn_s_setprio(1);
#pragma unroll
      for (int n = 0; n < 4; ++n) {
        acc[4][n] = __builtin_amdgcn_mfma_f32_16x16x32_bf16(a0, b1_[n], acc[4][n], 0, 0, 0);
        acc[5][n] = __builtin_amdgcn_mfma_f32_16x16x32_bf16(a1, b1_[n], acc[5][n], 0, 0, 0);
        acc[6][n] = __builtin_amdgcn_mfma_f32_16x16x32_bf16(a2, b1_[n], acc[6][n], 0, 0, 0);
        acc[7][n] = __builtin_amdgcn_mfma_f32_16x16x32_bf16(a3, b1_[n], acc[7][n], 0, 0, 0);
      }
      __builtin_amdgcn_s_setprio(0);
      asm volatile("s_waitcnt vmcnt(2)" ::: "memory");  // drain B*(t+1), A0,A2(t+1)
      asm volatile("s_barrier" ::: "memory");
    }
  }
  asm volatile("s_waitcnt vmcnt(0)" ::: "memory");  // drain wrap-stage

  // epilogue: frag row=(lane>>4)*4+j, col=lane&15
#pragma unroll
  for (int m = 0; m < 8; ++m) {
#pragma unroll
    for (int j = 0; j < 4; ++j) {
      const int rl = wr * 128 + m * 16 + ((lane >> 4) << 2) + j;
      const size_t row = (size_t)bm * 256 + rl;
      float sc = 1.0f;
      if constexpr (SCALE) sc = aux[row];
      float part = 0.f;
#pragma unroll
      for (int n = 0; n < 4; ++n) {
        const int col = bn * 256 + wc * 64 + n * 16 + (lane & 15);
        float x = acc[m][n][j];
        if constexpr (SCALE) x *= sc;
        x += bias[col];
        if constexpr (RELU) x = fmaxf(x, 0.f);
        if constexpr (ACC_PART) part += x * x;
        if constexpr (OUT_BF16)
          ((unsigned short*)Cptr)[row * (size_t)N + col] = f2bf(x);
        else
          ((float*)Cptr)[row * (size_t)N + col] = x;
      }
      if constexpr (ACC_PART) {
        // reduce across the 16 lanes holding this row (lane>>4 fixed)
        part += __shfl_xor(part, 1, 64);
        part += __shfl_xor(part, 2, 64);
        part += __shfl_xor(part, 4, 64);
        part += __shfl_xor(part, 8, 64);
        if ((lane & 15) == 0)
          aux[row * (size_t)(numBN * 4) + bn * 4 + wc] = part;
      }
    }
  }
}

// 2-phase GEMM for G3 (tiny-N, memory-bound)
template <int BM, int BN, int WN, bool RELU, bool OUT_BF16>
__global__ __launch_bounds__(256) void gemm_ff(
    const unsigned short* __restrict__ A, const unsigned short* __restrict__ Bw,
    const float* __restrict__ bias, void* __restrict__ Cptr,
    int M, int N, int K) {
  constexpr int BK = 32;
  constexpr int PTA = BM / 64;
  constexpr int PTB = BN / 64;
  __shared__ short As[BM * BK];
  __shared__ short Bs[BN * BK];

  const int t = threadIdx.x;
  const int lane = t & 63;
  const int wid = t >> 6;
  const int wr = wid / WN;
  const int wc = wid % WN;
  const int bm = blockIdx.x;
  const int bn = blockIdx.y;

  f32x4 acc[4][4] = {};
  const unsigned short* Abase = A + (size_t)bm * BM * K;
  const unsigned short* Bbase = Bw + (size_t)bn * BN * K;
  const int kIters = K / BK;
  for (int kk = 0; kk < kIters; ++kk) {
    const int k0 = kk * BK;
#pragma unroll
    for (int r = 0; r < PTB; ++r) {
      const int s = r * 256 + t;
      gll16(Bbase + (size_t)(s >> 2) * K + k0 + (s & 3) * 8, &Bs[s * 8]);
    }
#pragma unroll
    for (int r = 0; r < PTA; ++r) {
      const int s = r * 256 + t;
      gll16(Abase + (size_t)(s >> 2) * K + k0 + (s & 3) * 8, &As[s * 8]);
    }
    __syncthreads();
    short8 af[4], bfg[4];
#pragma unroll
    for (int m = 0; m < 4; ++m)
      af[m] = *(const short8*)&As[(wr * 64 + m * 16 + (lane & 15)) * BK + ((lane >> 4) * 8)];
#pragma unroll
    for (int n = 0; n < 4; ++n)
      bfg[n] = *(const short8*)&Bs[(wc * 64 + n * 16 + (lane & 15)) * BK + ((lane >> 4) * 8)];
#pragma unroll
    for (int m = 0; m < 4; ++m)
#pragma unroll
      for (int n = 0; n < 4; ++n)
        acc[m][n] = __builtin_amdgcn_mfma_f32_16x16x32_bf16(af[m], bfg[n], acc[m][n], 0, 0, 0);
    __syncthreads();
  }

#pragma unroll
  for (int m = 0; m < 4; ++m) {
#pragma unroll
    for (int j = 0; j < 4; ++j) {
      const int rl = wr * 64 + m * 16 + ((lane >> 4) << 2) + j;
      const size_t row = (size_t)bm * BM + rl;
#pragma unroll
      for (int n = 0; n < 4; ++n) {
        const int col = bn * BN + wc * 64 + n * 16 + (lane & 15);
        float v = acc[m][n][j];
        v += bias[col];
        if constexpr (RELU) v = fmaxf(v, 0.f);
        if constexpr (OUT_BF16)
          ((unsigned short*)Cptr)[row * (size_t)N + col] = f2bf(v);
        else
          ((float*)Cptr)[row * (size_t)N + col] = v;
      }
    }
  }
}

extern "C" void kernel_launch(void* const* d_in, const int* in_sizes, int n_in,
                              void* d_out, int out_size, void* d_ws, size_t ws_size,
                              hipStream_t stream) {
  const float* states = (const float*)d_in[0];
  const float* W1 = (const float*)d_in[1];
  const float* b1 = (const float*)d_in[2];
  const float* W2 = (const float*)d_in[3];
  const float* b2 = (const float*)d_in[4];
  const float* Wq = (const float*)d_in[5];
  const float* bq = (const float*)d_in[6];
  float* out = (float*)d_out;

  const int D = 1024, H1 = 2048, H2 = 1024, AO = 64;
  const int B = in_sizes[0] / D;

  unsigned short* W1b = (unsigned short*)d_ws;  // [H1][D]
  unsigned short* W2b = W1b + (size_t)H1 * D;   // [H2][H1]
  unsigned short* Wqb = W2b + (size_t)H2 * H1;  // [AO][H2]
  char* dynbase = (char*)(Wqb + (size_t)AO * H2);

  const size_t wbytes = ((size_t)H1 * D + (size_t)H2 * H1 + (size_t)AO * H2) * 2;
  size_t avail = ws_size > wbytes ? ws_size - wbytes : 0;
  // per-row: scale(4) + partial(32*4=128) + sn(D*2) + h1(H1*2) + h2(H2*2)
  const size_t per_row = 4 + 128 + (size_t)(D + H1 + H2) * 2;
  long long bc = (long long)(avail / per_row);
  bc = (bc / 256) * 256;
  if (bc <= 0) bc = 256;
  if (bc > B) bc = B;

  float* scale1 = (float*)dynbase;
  float* partial = scale1 + bc;                       // [bc][32]
  unsigned short* sn = (unsigned short*)(partial + (size_t)bc * 32);
  unsigned short* h1 = sn + (size_t)bc * D;
  unsigned short* h2 = h1 + (size_t)bc * H1;

  // allow 128 KiB dynamic LDS (host-side attribute set; capture-safe)
  (void)hipFuncSetAttribute((const void*)gemm_p8<true, false, true, true>,
                            hipFuncAttributeMaxDynamicSharedMemorySize, 131072);
  (void)hipFuncSetAttribute((const void*)gemm_p8<false, true, true, true>,
                            hipFuncAttributeMaxDynamicSharedMemorySize, 131072);

  cvt_w3<<<dim3(2048), dim3(256), 0, stream>>>(W1, W2, Wq, W1b, W2b, Wqb,
                                               H1 * D, H2 * H1, AO * H2);

  for (int off = 0; off < B; off += (int)bc) {
    const int cur = (B - off) < (int)bc ? (B - off) : (int)bc;
    norm_rows_f32<1024><<<dim3(cur / 4), dim3(256), 0, stream>>>(
        states + (size_t)off * D, sn, cur);
    // G1: h1 = relu(sn·W1^T + b1); writes ssq partials to `partial`
    gemm_p8<true, false, true, true>
        <<<dim3((cur / 256) * (H1 / 256)), dim3(512), 131072, stream>>>(
            sn, W1b, b1, partial, h1, cur, H1, D);
    // scale1[row] = 1/(sqrt(sum partials)+eps)
    reduce_scale<<<dim3((cur + 255) / 256), dim3(256), 0, stream>>>(
        partial, scale1, cur, (H1 / 256) * 4);
    // G2: h2 = relu(scale1·(h1·W2^T) + b2)
    gemm_p8<false, true, true, true>
        <<<dim3((cur / 256) * (H2 / 256)), dim3(512), 131072, stream>>>(
            h1, W2b, b2, scale1, h2, cur, H2, H1);
    // G3: q = h2·Wq^T + bq
    gemm_ff<256, 64, 1, false, false>
        <<<dim3(cur / 256), dim3(256), 0, stream>>>(
            h2, Wqb, bq, out + (size_t)off * AO, cur, AO, H2);
  }
}

// Round 18
// 654.961 us; speedup vs baseline: 3.1004x; 1.0014x over previous
//
#include <hip/hip_runtime.h>
#include <stdint.h>

typedef __attribute__((ext_vector_type(8))) short short8;
typedef __attribute__((ext_vector_type(4))) short short4v;
typedef __attribute__((ext_vector_type(4))) float f32x4;

#define DEVINL __device__ __forceinline__

DEVINL unsigned short f2bf(float x) {
  uint32_t b = __float_as_uint(x);
  b += 0x7fffu + ((b >> 16) & 1u);
  return (unsigned short)(b >> 16);
}
DEVINL float bf2f(unsigned short u) {
  return __uint_as_float(((uint32_t)u) << 16);
}

DEVINL void gll16(const void* g, void* l) {
  __builtin_amdgcn_global_load_lds(
      (const __attribute__((address_space(1))) uint32_t*)g,
      (__attribute__((address_space(3))) uint32_t*)l, 16, 0, 0);
}

// one launch converts all three weight matrices to bf16
__global__ void cvt_w3(const float* __restrict__ W1, const float* __restrict__ W2,
                       const float* __restrict__ Wq, unsigned short* __restrict__ o1,
                       unsigned short* __restrict__ o2, unsigned short* __restrict__ oq,
                       int n1, int n2, int nq) {
  int i = blockIdx.x * blockDim.x + threadIdx.x;
  const int st = gridDim.x * blockDim.x;
  const int tot = n1 + n2 + nq;
  for (; i < tot; i += st) {
    if (i < n1)
      o1[i] = f2bf(W1[i]);
    else if (i < n1 + n2)
      o2[i - n1] = f2bf(W2[i - n1]);
    else
      oq[i - n1 - n2] = f2bf(Wq[i - n1 - n2]);
  }
}

// wave-per-row: out_row = bf16(in_row / (||in_row|| + eps))
template <int D>
__global__ __launch_bounds__(256) void norm_rows_f32(
    const float* __restrict__ in, unsigned short* __restrict__ out, int nrows) {
  const int lane = threadIdx.x & 63;
  const int row = blockIdx.x * 4 + (threadIdx.x >> 6);
  if (row >= nrows) return;
  const float* r = in + (size_t)row * D;
  constexpr int NSEG = D / 256;
  f32x4 v[NSEG];
  float ssq = 0.f;
#pragma unroll
  for (int i = 0; i < NSEG; ++i) {
    v[i] = *(const f32x4*)(r + (i * 64 + lane) * 4);
#pragma unroll
    for (int j = 0; j < 4; ++j) ssq += v[i][j] * v[i][j];
  }
#pragma unroll
  for (int m = 32; m >= 1; m >>= 1) ssq += __shfl_xor(ssq, m, 64);
  const float sc = 1.0f / (sqrtf(ssq) + 1e-8f);
  unsigned short* o = out + (size_t)row * D;
#pragma unroll
  for (int i = 0; i < NSEG; ++i) {
    short4v u;
#pragma unroll
    for (int j = 0; j < 4; ++j) u[j] = (short)f2bf(v[i][j] * sc);
    *(short4v*)(o + (i * 64 + lane) * 4) = u;
  }
}

// scale[row] = 1/(sqrt(sum of np partials)+eps)
__global__ __launch_bounds__(256) void reduce_scale(
    const float* __restrict__ part, float* __restrict__ scale, int nrows, int np) {
  const int row = blockIdx.x * blockDim.x + threadIdx.x;
  if (row >= nrows) return;
  const float* p = part + (size_t)row * np;
  float s = 0.f;
  for (int i = 0; i < np; i += 4) {
    f32x4 v = *(const f32x4*)(p + i);
    s += v[0] + v[1] + v[2] + v[3];
  }
  scale[row] = 1.0f / (sqrtf(s) + 1e-8f);
}

// 256x256 counted-vmcnt 4-phase GEMM — r10/r16-validated ledger (PASS x3).
// BK=64, 8 waves (2Mx4N), per-wave C = 128x64 (acc 8x4). Dbuf LDS 128 KiB.
// CONSUMPTION map (per wave): PH0/PH1 read dB0..dB3 + dA0 (wr=0) / dA2
// (wr=1); PH2/PH3 read dA1 (wr=0) / dA3 (wr=1).
// Issue order of tile t+1's 8 gll16 (2/phase):
//   PH0: B0,B1 | PH1: B2,B3 | PH2: A0,A2 | PH3: A1,A3
// Waits (counted, NEVER 0 in loop):
//   PH1-end vmcnt(4): drains A1,A3(t) -> PH2/PH3 reads of dA1/dA3(cur) safe.
//   PH3-end vmcnt(2): drains all but A1,A3(t+1) -> next PH0/PH1 reads safe.
// Prologue B0..B3,A0,A2,A1,A3 + vmcnt(2) leaves exactly A1,A3 in flight.
// r18: sched_barrier(0) RESTORED — r17 A/B showed its removal cost ~20 us
// per GEMM dispatch (MfmaUtil 38.4->35.8, VALUBusy 25->28: the scheduler
// hoisted next-phase VALU into the MFMA window). The fence is part of this
// schedule's validated envelope; m141's "don't pin" applies to
// compiler-scheduled loops, not this hand-jailed 4-phase.
// T2 involution swizzle (128B rows): stored 16B-unit at pos p of row r is
// global unit p^(r&7); ds_read pos u^(r&7), r&7==lane&7 -> 0 conflicts.
// ACC_PART (G1): epilogue writes per-(row, bn, wc) partial ssq of the
// post-relu outputs to aux[row*(numBN*4) + bn*4 + wc] — each slot written
// exactly once (no atomics, deterministic). SCALE (G2): multiply row by
// aux[row] before bias.
template <bool ACC_PART, bool SCALE, bool RELU, bool OUT_BF16>
__global__ __launch_bounds__(512, 1) void gemm_p8(
    const unsigned short* __restrict__ A, const unsigned short* __restrict__ Bw,
    const float* __restrict__ bias, float* __restrict__ aux,
    void* __restrict__ Cptr, int M, int N, int K) {
  extern __shared__ __align__(16) short lds[];  // 2 x (A[256][64] | B[256][64])

  const int t = threadIdx.x;
  const int lane = t & 63;
  const int wid = t >> 6;   // 0..7
  const int wr = wid >> 2;  // 0..1  (128-row half)
  const int wc = wid & 3;   // 0..3  (64-col quarter)

  const int nwg = gridDim.x;
  const int bid = blockIdx.x;
  int wg = bid;
  if ((nwg & 7) == 0) wg = (bid & 7) * (nwg >> 3) + (bid >> 3);
  const int numBN = N >> 8;
  const int bm = wg / numBN;
  const int bn = wg % numBN;

  // Staging: thread t covers row (t>>3)+j*64 (j=0..3), 16B-unit pos t&7.
  // Pre-swizzled source: global unit = (t&7) ^ (row&7); row&7 == (t>>3)&7.
  const int row0 = t >> 3;
  const int usrc = ((t & 7) ^ (row0 & 7)) << 3;
  const unsigned short* sA0 = A + (size_t)(bm * 256 + row0) * K + usrc;
  const unsigned short* sA1 = A + (size_t)(bm * 256 + 64 + row0) * K + usrc;
  const unsigned short* sA2 = A + (size_t)(bm * 256 + 128 + row0) * K + usrc;
  const unsigned short* sA3 = A + (size_t)(bm * 256 + 192 + row0) * K + usrc;
  const unsigned short* sB0 = Bw + (size_t)(bn * 256 + row0) * K + usrc;
  const unsigned short* sB1 = Bw + (size_t)(bn * 256 + 64 + row0) * K + usrc;
  const unsigned short* sB2 = Bw + (size_t)(bn * 256 + 128 + row0) * K + usrc;
  const unsigned short* sB3 = Bw + (size_t)(bn * 256 + 192 + row0) * K + usrc;
  const int dA0 = t * 8, dA1 = 4096 + t * 8, dA2 = 8192 + t * 8, dA3 = 12288 + t * 8;
  const int dB0 = 16384 + t * 8, dB1 = 20480 + t * 8, dB2 = 24576 + t * 8, dB3 = 28672 + t * 8;

  // ds_read: row r, global unit u = kh*4+(lane>>4) -> pos u^(r&7); r&7==lane&7.
  const int sw = lane & 7;
  const int pA = (wr * 128 + (lane & 15)) * 64;
  const int pB = 16384 + (wc * 64 + (lane & 15)) * 64;
  const int pu0 = (((lane >> 4)) ^ sw) * 8;
  const int pu1 = ((4 | (lane >> 4)) ^ sw) * 8;

  f32x4 acc[8][4] = {};
  const int nt = K >> 6;

  // prologue: stage tile 0; A1,A3 LAST so vmcnt(2) leaves exactly them in flight
  gll16(sB0, &lds[dB0]);
  gll16(sB1, &lds[dB1]);
  gll16(sB2, &lds[dB2]);
  gll16(sB3, &lds[dB3]);
  gll16(sA0, &lds[dA0]);
  gll16(sA2, &lds[dA2]);
  gll16(sA1, &lds[dA1]);
  gll16(sA3, &lds[dA3]);
  asm volatile("s_waitcnt vmcnt(2)" ::: "memory");
  asm volatile("s_barrier" ::: "memory");

  for (int tt = 0; tt < nt; ++tt) {
    const int cb = (tt & 1) << 15;  // current buf (shorts)
    const int nb = cb ^ 32768;
    int kf = tt + 1;
    if (kf == nt) kf = 0;  // wrap-stage (unused, keeps vmcnt uniform)
    const int kn = kf * 64;
    short8 b0_[4], b1_[4];
    // ---------- PH0: (mh=0, kh=0); issue B0,B1(t+1) ----------
    {
      const short8 a0 = *(const short8*)&lds[cb + pA + 0 * 1024 + pu0];
      const short8 a1 = *(const short8*)&lds[cb + pA + 1 * 1024 + pu0];
      const short8 a2 = *(const short8*)&lds[cb + pA + 2 * 1024 + pu0];
      const short8 a3 = *(const short8*)&lds[cb + pA + 3 * 1024 + pu0];
#pragma unroll
      for (int n = 0; n < 4; ++n)
        b0_[n] = *(const short8*)&lds[cb + pB + n * 1024 + pu0];
      gll16(sB0 + kn, &lds[nb + dB0]);
      gll16(sB1 + kn, &lds[nb + dB1]);
      asm volatile("s_barrier" ::: "memory");
      asm volatile("s_waitcnt lgkmcnt(0)" ::: "memory");
      __builtin_amdgcn_sched_barrier(0);
      __builtin_amdgcn_s_setprio(1);
#pragma unroll
      for (int n = 0; n < 4; ++n) {
        acc[0][n] = __builtin_amdgcn_mfma_f32_16x16x32_bf16(a0, b0_[n], acc[0][n], 0, 0, 0);
        acc[1][n] = __builtin_amdgcn_mfma_f32_16x16x32_bf16(a1, b0_[n], acc[1][n], 0, 0, 0);
        acc[2][n] = __builtin_amdgcn_mfma_f32_16x16x32_bf16(a2, b0_[n], acc[2][n], 0, 0, 0);
        acc[3][n] = __builtin_amdgcn_mfma_f32_16x16x32_bf16(a3, b0_[n], acc[3][n], 0, 0, 0);
      }
      __builtin_amdgcn_s_setprio(0);
      asm volatile("s_barrier" ::: "memory");
    }
    // ---------- PH1: (mh=0, kh=1); issue B2,B3(t+1); vmcnt(4) ----------
    {
      const short8 a0 = *(const short8*)&lds[cb + pA + 0 * 1024 + pu1];
      const short8 a1 = *(const short8*)&lds[cb + pA + 1 * 1024 + pu1];
      const short8 a2 = *(const short8*)&lds[cb + pA + 2 * 1024 + pu1];
      const short8 a3 = *(const short8*)&lds[cb + pA + 3 * 1024 + pu1];
#pragma unroll
      for (int n = 0; n < 4; ++n)
        b1_[n] = *(const short8*)&lds[cb + pB + n * 1024 + pu1];
      gll16(sB2 + kn, &lds[nb + dB2]);
      gll16(sB3 + kn, &lds[nb + dB3]);
      asm volatile("s_barrier" ::: "memory");
      asm volatile("s_waitcnt lgkmcnt(0)" ::: "memory");
      __builtin_amdgcn_sched_barrier(0);
      __builtin_amdgcn_s_setprio(1);
#pragma unroll
      for (int n = 0; n < 4; ++n) {
        acc[0][n] = __builtin_amdgcn_mfma_f32_16x16x32_bf16(a0, b1_[n], acc[0][n], 0, 0, 0);
        acc[1][n] = __builtin_amdgcn_mfma_f32_16x16x32_bf16(a1, b1_[n], acc[1][n], 0, 0, 0);
        acc[2][n] = __builtin_amdgcn_mfma_f32_16x16x32_bf16(a2, b1_[n], acc[2][n], 0, 0, 0);
        acc[3][n] = __builtin_amdgcn_mfma_f32_16x16x32_bf16(a3, b1_[n], acc[3][n], 0, 0, 0);
      }
      __builtin_amdgcn_s_setprio(0);
      asm volatile("s_waitcnt vmcnt(4)" ::: "memory");  // drain A1,A3(t)
      asm volatile("s_barrier" ::: "memory");
    }
    // ---------- PH2: (mh=1, kh=0); issue A0,A2(t+1) ----------
    {
      const short8 a0 = *(const short8*)&lds[cb + pA + 4 * 1024 + pu0];
      const short8 a1 = *(const short8*)&lds[cb + pA + 5 * 1024 + pu0];
      const short8 a2 = *(const short8*)&lds[cb + pA + 6 * 1024 + pu0];
      const short8 a3 = *(const short8*)&lds[cb + pA + 7 * 1024 + pu0];
      gll16(sA0 + kn, &lds[nb + dA0]);
      gll16(sA2 + kn, &lds[nb + dA2]);
      asm volatile("s_barrier" ::: "memory");
      asm volatile("s_waitcnt lgkmcnt(0)" ::: "memory");
      __builtin_amdgcn_sched_barrier(0);
      __builtin_amdgcn_s_setprio(1);
#pragma unroll
      for (int n = 0; n < 4; ++n) {
        acc[4][n] = __builtin_amdgcn_mfma_f32_16x16x32_bf16(a0, b0_[n], acc[4][n], 0, 0, 0);
        acc[5][n] = __builtin_amdgcn_mfma_f32_16x16x32_bf16(a1, b0_[n], acc[5][n], 0, 0, 0);
        acc[6][n] = __builtin_amdgcn_mfma_f32_16x16x32_bf16(a2, b0_[n], acc[6][n], 0, 0, 0);
        acc[7][n] = __builtin_amdgcn_mfma_f32_16x16x32_bf16(a3, b0_[n], acc[7][n], 0, 0, 0);
      }
      __builtin_amdgcn_s_setprio(0);
      asm volatile("s_barrier" ::: "memory");
    }
    // ---------- PH3: (mh=1, kh=1); issue A1,A3(t+1); vmcnt(2) ----------
    {
      const short8 a0 = *(const short8*)&lds[cb + pA + 4 * 1024 + pu1];
      const short8 a1 = *(const short8*)&lds[cb + pA + 5 * 1024 + pu1];
      const short8 a2 = *(const short8*)&lds[cb + pA + 6 * 1024 + pu1];
      const short8 a3 = *(const short8*)&lds[cb + pA + 7 * 1024 + pu1];
      gll16(sA1 + kn, &lds[nb + dA1]);
      gll16(sA3 + kn, &lds[nb + dA3]);
      asm volatile("s_barrier" ::: "memory");
      asm volatile("s_waitcnt lgkmcnt(0)" ::: "memory");
      __builtin_amdgcn_sched_barrier(0);
      __builtin_amdgcn_s_setprio(1);
#pragma unroll
      for (int n = 0; n < 4; ++n) {
        acc[4][n] = __builtin_amdgcn_mfma_f32_16x16x32_bf16(a0, b1_[n], acc[4][n], 0, 0, 0);
        acc[5][n] = __builtin_amdgcn_mfma_f32_16x16x32_bf16(a1, b1_[n], acc[5][n], 0, 0, 0);
        acc[6][n] = __builtin_amdgcn_mfma_f32_16x16x32_bf16(a2, b1_[n], acc[6][n], 0, 0, 0);
        acc[7][n] = __builtin_amdgcn_mfma_f32_16x16x32_bf16(a3, b1_[n], acc[7][n], 0, 0, 0);
      }
      __builtin_amdgcn_s_setprio(0);
      asm volatile("s_waitcnt vmcnt(2)" ::: "memory");  // drain B*(t+1), A0,A2(t+1)
      asm volatile("s_barrier" ::: "memory");
    }
  }
  asm volatile("s_waitcnt vmcnt(0)" ::: "memory");  // drain wrap-stage

  // epilogue: frag row=(lane>>4)*4+j, col=lane&15
#pragma unroll
  for (int m = 0; m < 8; ++m) {
#pragma unroll
    for (int j = 0; j < 4; ++j) {
      const int rl = wr * 128 + m * 16 + ((lane >> 4) << 2) + j;
      const size_t row = (size_t)bm * 256 + rl;
      float sc = 1.0f;
      if constexpr (SCALE) sc = aux[row];
      float part = 0.f;
#pragma unroll
      for (int n = 0; n < 4; ++n) {
        const int col = bn * 256 + wc * 64 + n * 16 + (lane & 15);
        float x = acc[m][n][j];
        if constexpr (SCALE) x *= sc;
        x += bias[col];
        if constexpr (RELU) x = fmaxf(x, 0.f);
        if constexpr (ACC_PART) part += x * x;
        if constexpr (OUT_BF16)
          ((unsigned short*)Cptr)[row * (size_t)N + col] = f2bf(x);
        else
          ((float*)Cptr)[row * (size_t)N + col] = x;
      }
      if constexpr (ACC_PART) {
        // reduce across the 16 lanes holding this row (lane>>4 fixed)
        part += __shfl_xor(part, 1, 64);
        part += __shfl_xor(part, 2, 64);
        part += __shfl_xor(part, 4, 64);
        part += __shfl_xor(part, 8, 64);
        if ((lane & 15) == 0)
          aux[row * (size_t)(numBN * 4) + bn * 4 + wc] = part;
      }
    }
  }
}

// 2-phase GEMM for G3 (tiny-N, memory-bound)
template <int BM, int BN, int WN, bool RELU, bool OUT_BF16>
__global__ __launch_bounds__(256) void gemm_ff(
    const unsigned short* __restrict__ A, const unsigned short* __restrict__ Bw,
    const float* __restrict__ bias, void* __restrict__ Cptr,
    int M, int N, int K) {
  constexpr int BK = 32;
  constexpr int PTA = BM / 64;
  constexpr int PTB = BN / 64;
  __shared__ short As[BM * BK];
  __shared__ short Bs[BN * BK];

  const int t = threadIdx.x;
  const int lane = t & 63;
  const int wid = t >> 6;
  const int wr = wid / WN;
  const int wc = wid % WN;
  const int bm = blockIdx.x;
  const int bn = blockIdx.y;

  f32x4 acc[4][4] = {};
  const unsigned short* Abase = A + (size_t)bm * BM * K;
  const unsigned short* Bbase = Bw + (size_t)bn * BN * K;
  const int kIters = K / BK;
  for (int kk = 0; kk < kIters; ++kk) {
    const int k0 = kk * BK;
#pragma unroll
    for (int r = 0; r < PTB; ++r) {
      const int s = r * 256 + t;
      gll16(Bbase + (size_t)(s >> 2) * K + k0 + (s & 3) * 8, &Bs[s * 8]);
    }
#pragma unroll
    for (int r = 0; r < PTA; ++r) {
      const int s = r * 256 + t;
      gll16(Abase + (size_t)(s >> 2) * K + k0 + (s & 3) * 8, &As[s * 8]);
    }
    __syncthreads();
    short8 af[4], bfg[4];
#pragma unroll
    for (int m = 0; m < 4; ++m)
      af[m] = *(const short8*)&As[(wr * 64 + m * 16 + (lane & 15)) * BK + ((lane >> 4) * 8)];
#pragma unroll
    for (int n = 0; n < 4; ++n)
      bfg[n] = *(const short8*)&Bs[(wc * 64 + n * 16 + (lane & 15)) * BK + ((lane >> 4) * 8)];
#pragma unroll
    for (int m = 0; m < 4; ++m)
#pragma unroll
      for (int n = 0; n < 4; ++n)
        acc[m][n] = __builtin_amdgcn_mfma_f32_16x16x32_bf16(af[m], bfg[n], acc[m][n], 0, 0, 0);
    __syncthreads();
  }

#pragma unroll
  for (int m = 0; m < 4; ++m) {
#pragma unroll
    for (int j = 0; j < 4; ++j) {
      const int rl = wr * 64 + m * 16 + ((lane >> 4) << 2) + j;
      const size_t row = (size_t)bm * BM + rl;
#pragma unroll
      for (int n = 0; n < 4; ++n) {
        const int col = bn * BN + wc * 64 + n * 16 + (lane & 15);
        float v = acc[m][n][j];
        v += bias[col];
        if constexpr (RELU) v = fmaxf(v, 0.f);
        if constexpr (OUT_BF16)
          ((unsigned short*)Cptr)[row * (size_t)N + col] = f2bf(v);
        else
          ((float*)Cptr)[row * (size_t)N + col] = v;
      }
    }
  }
}

extern "C" void kernel_launch(void* const* d_in, const int* in_sizes, int n_in,
                              void* d_out, int out_size, void* d_ws, size_t ws_size,
                              hipStream_t stream) {
  const float* states = (const float*)d_in[0];
  const float* W1 = (const float*)d_in[1];
  const float* b1 = (const float*)d_in[2];
  const float* W2 = (const float*)d_in[3];
  const float* b2 = (const float*)d_in[4];
  const float* Wq = (const float*)d_in[5];
  const float* bq = (const float*)d_in[6];
  float* out = (float*)d_out;

  const int D = 1024, H1 = 2048, H2 = 1024, AO = 64;
  const int B = in_sizes[0] / D;

  unsigned short* W1b = (unsigned short*)d_ws;  // [H1][D]
  unsigned short* W2b = W1b + (size_t)H1 * D;   // [H2][H1]
  unsigned short* Wqb = W2b + (size_t)H2 * H1;  // [AO][H2]
  char* dynbase = (char*)(Wqb + (size_t)AO * H2);

  const size_t wbytes = ((size_t)H1 * D + (size_t)H2 * H1 + (size_t)AO * H2) * 2;
  size_t avail = ws_size > wbytes ? ws_size - wbytes : 0;
  // per-row: scale(4) + partial(32*4=128) + sn(D*2) + h1(H1*2) + h2(H2*2)
  const size_t per_row = 4 + 128 + (size_t)(D + H1 + H2) * 2;
  long long bc = (long long)(avail / per_row);
  bc = (bc / 256) * 256;
  if (bc <= 0) bc = 256;
  if (bc > B) bc = B;

  float* scale1 = (float*)dynbase;
  float* partial = scale1 + bc;                       // [bc][32]
  unsigned short* sn = (unsigned short*)(partial + (size_t)bc * 32);
  unsigned short* h1 = sn + (size_t)bc * D;
  unsigned short* h2 = h1 + (size_t)bc * H1;

  // allow 128 KiB dynamic LDS (host-side attribute set; capture-safe)
  (void)hipFuncSetAttribute((const void*)gemm_p8<true, false, true, true>,
                            hipFuncAttributeMaxDynamicSharedMemorySize, 131072);
  (void)hipFuncSetAttribute((const void*)gemm_p8<false, true, true, true>,
                            hipFuncAttributeMaxDynamicSharedMemorySize, 131072);

  cvt_w3<<<dim3(2048), dim3(256), 0, stream>>>(W1, W2, Wq, W1b, W2b, Wqb,
                                               H1 * D, H2 * H1, AO * H2);

  for (int off = 0; off < B; off += (int)bc) {
    const int cur = (B - off) < (int)bc ? (B - off) : (int)bc;
    norm_rows_f32<1024><<<dim3(cur / 4), dim3(256), 0, stream>>>(
        states + (size_t)off * D, sn, cur);
    // G1: h1 = relu(sn·W1^T + b1); writes ssq partials to `partial`
    gemm_p8<true, false, true, true>
        <<<dim3((cur / 256) * (H1 / 256)), dim3(512), 131072, stream>>>(
            sn, W1b, b1, partial, h1, cur, H1, D);
    // scale1[row] = 1/(sqrt(sum partials)+eps)
    reduce_scale<<<dim3((cur + 255) / 256), dim3(256), 0, stream>>>(
        partial, scale1, cur, (H1 / 256) * 4);
    // G2: h2 = relu(scale1·(h1·W2^T) + b2)
    gemm_p8<false, true, true, true>
        <<<dim3((cur / 256) * (H2 / 256)), dim3(512), 131072, stream>>>(
            h1, W2b, b2, scale1, h2, cur, H2, H1);
    // G3: q = h2·Wq^T + bq
    gemm_ff<256, 64, 1, false, false>
        <<<dim3(cur / 256), dim3(256), 0, stream>>>(
            h2, Wqb, bq, out + (size_t)off * AO, cur, AO, H2);
  }
}

// Round 19
// 643.388 us; speedup vs baseline: 3.1562x; 1.0180x over previous
//
#include <hip/hip_runtime.h>
#include <stdint.h>

typedef __attribute__((ext_vector_type(8))) short short8;
typedef __attribute__((ext_vector_type(4))) short short4v;
typedef __attribute__((ext_vector_type(4))) float f32x4;

#define DEVINL __device__ __forceinline__

DEVINL unsigned short f2bf(float x) {
  uint32_t b = __float_as_uint(x);
  b += 0x7fffu + ((b >> 16) & 1u);
  return (unsigned short)(b >> 16);
}
DEVINL float bf2f(unsigned short u) {
  return __uint_as_float(((uint32_t)u) << 16);
}

DEVINL void gll16(const void* g, void* l) {
  __builtin_amdgcn_global_load_lds(
      (const __attribute__((address_space(1))) uint32_t*)g,
      (__attribute__((address_space(3))) uint32_t*)l, 16, 0, 0);
}

// one launch converts all three weight matrices to bf16
__global__ void cvt_w3(const float* __restrict__ W1, const float* __restrict__ W2,
                       const float* __restrict__ Wq, unsigned short* __restrict__ o1,
                       unsigned short* __restrict__ o2, unsigned short* __restrict__ oq,
                       int n1, int n2, int nq) {
  int i = blockIdx.x * blockDim.x + threadIdx.x;
  const int st = gridDim.x * blockDim.x;
  const int tot = n1 + n2 + nq;
  for (; i < tot; i += st) {
    if (i < n1)
      o1[i] = f2bf(W1[i]);
    else if (i < n1 + n2)
      o2[i - n1] = f2bf(W2[i - n1]);
    else
      oq[i - n1 - n2] = f2bf(Wq[i - n1 - n2]);
  }
}

// wave-per-row: out_row = bf16(in_row / (||in_row|| + eps))
template <int D>
__global__ __launch_bounds__(256) void norm_rows_f32(
    const float* __restrict__ in, unsigned short* __restrict__ out, int nrows) {
  const int lane = threadIdx.x & 63;
  const int row = blockIdx.x * 4 + (threadIdx.x >> 6);
  if (row >= nrows) return;
  const float* r = in + (size_t)row * D;
  constexpr int NSEG = D / 256;
  f32x4 v[NSEG];
  float ssq = 0.f;
#pragma unroll
  for (int i = 0; i < NSEG; ++i) {
    v[i] = *(const f32x4*)(r + (i * 64 + lane) * 4);
#pragma unroll
    for (int j = 0; j < 4; ++j) ssq += v[i][j] * v[i][j];
  }
#pragma unroll
  for (int m = 32; m >= 1; m >>= 1) ssq += __shfl_xor(ssq, m, 64);
  const float sc = 1.0f / (sqrtf(ssq) + 1e-8f);
  unsigned short* o = out + (size_t)row * D;
#pragma unroll
  for (int i = 0; i < NSEG; ++i) {
    short4v u;
#pragma unroll
    for (int j = 0; j < 4; ++j) u[j] = (short)f2bf(v[i][j] * sc);
    *(short4v*)(o + (i * 64 + lane) * 4) = u;
  }
}

// scale[row] = 1/(sqrt(sum over slots of part[slot][row])+eps)
__global__ __launch_bounds__(256) void reduce_scale(
    const float* __restrict__ part, float* __restrict__ scale, int nrows, int np) {
  const int row = blockIdx.x * blockDim.x + threadIdx.x;
  if (row >= nrows) return;
  float s = 0.f;
  for (int i = 0; i < np; ++i) s += part[(size_t)i * nrows + row];
  scale[row] = 1.0f / (sqrtf(s) + 1e-8f);
}

// 256x256 counted-vmcnt 4-phase GEMM — r10/r16-validated ledger (PASS x5).
// BK=64, 8 waves (2Mx4N), per-wave C = 128x64 (acc 8x4). Dbuf LDS 128 KiB.
// CONSUMPTION map (per wave): PH0/PH1 read dB0..dB3 + dA0 (wr=0) / dA2
// (wr=1); PH2/PH3 read dA1 (wr=0) / dA3 (wr=1).
// r19 change — ISSUE-SLOT PERMUTATION (ledger identical, slack maximized):
//   PH0: A0,A2 | PH1: B0,B1 | PH2: B2,B3 | PH3: A1,A3
// Previously A0,A2 were issued at PH2 and drained at PH3-end — only 1 phase
// (~250 cyc) of slack against ~200-900 cyc L2/HBM latency; that wait ate
// ~300 cyc per K-tile (measured 1630 vs 1024 cyc LDS/MFMA floor). Now every
// load drained at a wait is >=2 phases old.
// Waits (counted, NEVER 0 in loop) — unchanged:
//   PH1-end vmcnt(4): outstanding = A1A3(t)[oldest] + A0A2,B0B1(t+1) = 6;
//     drains A1,A3(t) -> PH2/PH3 reads of dA1/dA3(cur) safe.
//   PH3-end vmcnt(2): outstanding = A0A2,B0B1,B2B3,A1A3(t+1) = 8;
//     drains all but A1,A3(t+1) -> next PH0/PH1 reads safe.
// Prologue A0,A2,B0..B3,A1,A3 + vmcnt(2) leaves exactly A1,A3 in flight.
// Cross-wave publish: every wave stages copies of every region and drains
// its OWN loads before each barrier (r5/r10-validated argument).
// T2 involution swizzle (128B rows): stored 16B-unit at pos p of row r is
// global unit p^(r&7); ds_read pos u^(r&7), r&7==lane&7 -> 0 conflicts.
// ACC_PART (G1): epilogue writes per-(slot,row) partial ssq to
// aux[(bn*4+wc)*M + row] — column-major so each writer lane's 4 j-values
// are consecutive and lanes 0/16/32/48 fill a 64B line (r18's row-major
// scatter caused partial-line RMW, +23 us). Each slot written exactly once.
// SCALE (G2): multiply row by aux[row] before bias.
template <bool ACC_PART, bool SCALE, bool RELU, bool OUT_BF16>
__global__ __launch_bounds__(512, 1) void gemm_p8(
    const unsigned short* __restrict__ A, const unsigned short* __restrict__ Bw,
    const float* __restrict__ bias, float* __restrict__ aux,
    void* __restrict__ Cptr, int M, int N, int K) {
  extern __shared__ __align__(16) short lds[];  // 2 x (A[256][64] | B[256][64])

  const int t = threadIdx.x;
  const int lane = t & 63;
  const int wid = t >> 6;   // 0..7
  const int wr = wid >> 2;  // 0..1  (128-row half)
  const int wc = wid & 3;   // 0..3  (64-col quarter)

  const int nwg = gridDim.x;
  const int bid = blockIdx.x;
  int wg = bid;
  if ((nwg & 7) == 0) wg = (bid & 7) * (nwg >> 3) + (bid >> 3);
  const int numBN = N >> 8;
  const int bm = wg / numBN;
  const int bn = wg % numBN;

  // Staging: thread t covers row (t>>3)+j*64 (j=0..3), 16B-unit pos t&7.
  // Pre-swizzled source: global unit = (t&7) ^ (row&7); row&7 == (t>>3)&7.
  const int row0 = t >> 3;
  const int usrc = ((t & 7) ^ (row0 & 7)) << 3;
  const unsigned short* sA0 = A + (size_t)(bm * 256 + row0) * K + usrc;
  const unsigned short* sA1 = A + (size_t)(bm * 256 + 64 + row0) * K + usrc;
  const unsigned short* sA2 = A + (size_t)(bm * 256 + 128 + row0) * K + usrc;
  const unsigned short* sA3 = A + (size_t)(bm * 256 + 192 + row0) * K + usrc;
  const unsigned short* sB0 = Bw + (size_t)(bn * 256 + row0) * K + usrc;
  const unsigned short* sB1 = Bw + (size_t)(bn * 256 + 64 + row0) * K + usrc;
  const unsigned short* sB2 = Bw + (size_t)(bn * 256 + 128 + row0) * K + usrc;
  const unsigned short* sB3 = Bw + (size_t)(bn * 256 + 192 + row0) * K + usrc;
  const int dA0 = t * 8, dA1 = 4096 + t * 8, dA2 = 8192 + t * 8, dA3 = 12288 + t * 8;
  const int dB0 = 16384 + t * 8, dB1 = 20480 + t * 8, dB2 = 24576 + t * 8, dB3 = 28672 + t * 8;

  // ds_read: row r, global unit u = kh*4+(lane>>4) -> pos u^(r&7); r&7==lane&7.
  const int sw = lane & 7;
  const int pA = (wr * 128 + (lane & 15)) * 64;
  const int pB = 16384 + (wc * 64 + (lane & 15)) * 64;
  const int pu0 = (((lane >> 4)) ^ sw) * 8;
  const int pu1 = ((4 | (lane >> 4)) ^ sw) * 8;

  f32x4 acc[8][4] = {};
  const int nt = K >> 6;

  // prologue: stage tile 0 in steady-state order; A1,A3 LAST so vmcnt(2)
  // leaves exactly them in flight
  gll16(sA0, &lds[dA0]);
  gll16(sA2, &lds[dA2]);
  gll16(sB0, &lds[dB0]);
  gll16(sB1, &lds[dB1]);
  gll16(sB2, &lds[dB2]);
  gll16(sB3, &lds[dB3]);
  gll16(sA1, &lds[dA1]);
  gll16(sA3, &lds[dA3]);
  asm volatile("s_waitcnt vmcnt(2)" ::: "memory");
  asm volatile("s_barrier" ::: "memory");

  for (int tt = 0; tt < nt; ++tt) {
    const int cb = (tt & 1) << 15;  // current buf (shorts)
    const int nb = cb ^ 32768;
    int kf = tt + 1;
    if (kf == nt) kf = 0;  // wrap-stage (unused, keeps vmcnt uniform)
    const int kn = kf * 64;
    short8 b0_[4], b1_[4];
    // ---------- PH0: (mh=0, kh=0); issue A0,A2(t+1) ----------
    {
      const short8 a0 = *(const short8*)&lds[cb + pA + 0 * 1024 + pu0];
      const short8 a1 = *(const short8*)&lds[cb + pA + 1 * 1024 + pu0];
      const short8 a2 = *(const short8*)&lds[cb + pA + 2 * 1024 + pu0];
      const short8 a3 = *(const short8*)&lds[cb + pA + 3 * 1024 + pu0];
#pragma unroll
      for (int n = 0; n < 4; ++n)
        b0_[n] = *(const short8*)&lds[cb + pB + n * 1024 + pu0];
      gll16(sA0 + kn, &lds[nb + dA0]);
      gll16(sA2 + kn, &lds[nb + dA2]);
      asm volatile("s_barrier" ::: "memory");
      asm volatile("s_waitcnt lgkmcnt(0)" ::: "memory");
      __builtin_amdgcn_sched_barrier(0);
      __builtin_amdgcn_s_setprio(1);
#pragma unroll
      for (int n = 0; n < 4; ++n) {
        acc[0][n] = __builtin_amdgcn_mfma_f32_16x16x32_bf16(a0, b0_[n], acc[0][n], 0, 0, 0);
        acc[1][n] = __builtin_amdgcn_mfma_f32_16x16x32_bf16(a1, b0_[n], acc[1][n], 0, 0, 0);
        acc[2][n] = __builtin_amdgcn_mfma_f32_16x16x32_bf16(a2, b0_[n], acc[2][n], 0, 0, 0);
        acc[3][n] = __builtin_amdgcn_mfma_f32_16x16x32_bf16(a3, b0_[n], acc[3][n], 0, 0, 0);
      }
      __builtin_amdgcn_s_setprio(0);
      asm volatile("s_barrier" ::: "memory");
    }
    // ---------- PH1: (mh=0, kh=1); issue B0,B1(t+1); vmcnt(4) ----------
    {
      const short8 a0 = *(const short8*)&lds[cb + pA + 0 * 1024 + pu1];
      const short8 a1 = *(const short8*)&lds[cb + pA + 1 * 1024 + pu1];
      const short8 a2 = *(const short8*)&lds[cb + pA + 2 * 1024 + pu1];
      const short8 a3 = *(const short8*)&lds[cb + pA + 3 * 1024 + pu1];
#pragma unroll
      for (int n = 0; n < 4; ++n)
        b1_[n] = *(const short8*)&lds[cb + pB + n * 1024 + pu1];
      gll16(sB0 + kn, &lds[nb + dB0]);
      gll16(sB1 + kn, &lds[nb + dB1]);
      asm volatile("s_barrier" ::: "memory");
      asm volatile("s_waitcnt lgkmcnt(0)" ::: "memory");
      __builtin_amdgcn_sched_barrier(0);
      __builtin_amdgcn_s_setprio(1);
#pragma unroll
      for (int n = 0; n < 4; ++n) {
        acc[0][n] = __builtin_amdgcn_mfma_f32_16x16x32_bf16(a0, b1_[n], acc[0][n], 0, 0, 0);
        acc[1][n] = __builtin_amdgcn_mfma_f32_16x16x32_bf16(a1, b1_[n], acc[1][n], 0, 0, 0);
        acc[2][n] = __builtin_amdgcn_mfma_f32_16x16x32_bf16(a2, b1_[n], acc[2][n], 0, 0, 0);
        acc[3][n] = __builtin_amdgcn_mfma_f32_16x16x32_bf16(a3, b1_[n], acc[3][n], 0, 0, 0);
      }
      __builtin_amdgcn_s_setprio(0);
      asm volatile("s_waitcnt vmcnt(4)" ::: "memory");  // drain A1,A3(t)
      asm volatile("s_barrier" ::: "memory");
    }
    // ---------- PH2: (mh=1, kh=0); issue B2,B3(t+1) ----------
    {
      const short8 a0 = *(const short8*)&lds[cb + pA + 4 * 1024 + pu0];
      const short8 a1 = *(const short8*)&lds[cb + pA + 5 * 1024 + pu0];
      const short8 a2 = *(const short8*)&lds[cb + pA + 6 * 1024 + pu0];
      const short8 a3 = *(const short8*)&lds[cb + pA + 7 * 1024 + pu0];
      gll16(sB2 + kn, &lds[nb + dB2]);
      gll16(sB3 + kn, &lds[nb + dB3]);
      asm volatile("s_barrier" ::: "memory");
      asm volatile("s_waitcnt lgkmcnt(0)" ::: "memory");
      __builtin_amdgcn_sched_barrier(0);
      __builtin_amdgcn_s_setprio(1);
#pragma unroll
      for (int n = 0; n < 4; ++n) {
        acc[4][n] = __builtin_amdgcn_mfma_f32_16x16x32_bf16(a0, b0_[n], acc[4][n], 0, 0, 0);
        acc[5][n] = __builtin_amdgcn_mfma_f32_16x16x32_bf16(a1, b0_[n], acc[5][n], 0, 0, 0);
        acc[6][n] = __builtin_amdgcn_mfma_f32_16x16x32_bf16(a2, b0_[n], acc[6][n], 0, 0, 0);
        acc[7][n] = __builtin_amdgcn_mfma_f32_16x16x32_bf16(a3, b0_[n], acc[7][n], 0, 0, 0);
      }
      __builtin_amdgcn_s_setprio(0);
      asm volatile("s_barrier" ::: "memory");
    }
    // ---------- PH3: (mh=1, kh=1); issue A1,A3(t+1); vmcnt(2) ----------
    {
      const short8 a0 = *(const short8*)&lds[cb + pA + 4 * 1024 + pu1];
      const short8 a1 = *(const short8*)&lds[cb + pA + 5 * 1024 + pu1];
      const short8 a2 = *(const short8*)&lds[cb + pA + 6 * 1024 + pu1];
      const short8 a3 = *(const short8*)&lds[cb + pA + 7 * 1024 + pu1];
      gll16(sA1 + kn, &lds[nb + dA1]);
      gll16(sA3 + kn, &lds[nb + dA3]);
      asm volatile("s_barrier" ::: "memory");
      asm volatile("s_waitcnt lgkmcnt(0)" ::: "memory");
      __builtin_amdgcn_sched_barrier(0);
      __builtin_amdgcn_s_setprio(1);
#pragma unroll
      for (int n = 0; n < 4; ++n) {
        acc[4][n] = __builtin_amdgcn_mfma_f32_16x16x32_bf16(a0, b1_[n], acc[4][n], 0, 0, 0);
        acc[5][n] = __builtin_amdgcn_mfma_f32_16x16x32_bf16(a1, b1_[n], acc[5][n], 0, 0, 0);
        acc[6][n] = __builtin_amdgcn_mfma_f32_16x16x32_bf16(a2, b1_[n], acc[6][n], 0, 0, 0);
        acc[7][n] = __builtin_amdgcn_mfma_f32_16x16x32_bf16(a3, b1_[n], acc[7][n], 0, 0, 0);
      }
      __builtin_amdgcn_s_setprio(0);
      asm volatile("s_waitcnt vmcnt(2)" ::: "memory");  // drain A0A2,B*(t+1)
      asm volatile("s_barrier" ::: "memory");
    }
  }
  asm volatile("s_waitcnt vmcnt(0)" ::: "memory");  // drain wrap-stage

  // epilogue: frag row=(lane>>4)*4+j, col=lane&15
#pragma unroll
  for (int m = 0; m < 8; ++m) {
#pragma unroll
    for (int j = 0; j < 4; ++j) {
      const int rl = wr * 128 + m * 16 + ((lane >> 4) << 2) + j;
      const size_t row = (size_t)bm * 256 + rl;
      float sc = 1.0f;
      if constexpr (SCALE) sc = aux[row];
      float part = 0.f;
#pragma unroll
      for (int n = 0; n < 4; ++n) {
        const int col = bn * 256 + wc * 64 + n * 16 + (lane & 15);
        float x = acc[m][n][j];
        if constexpr (SCALE) x *= sc;
        x += bias[col];
        if constexpr (RELU) x = fmaxf(x, 0.f);
        if constexpr (ACC_PART) part += x * x;
        if constexpr (OUT_BF16)
          ((unsigned short*)Cptr)[row * (size_t)N + col] = f2bf(x);
        else
          ((float*)Cptr)[row * (size_t)N + col] = x;
      }
      if constexpr (ACC_PART) {
        // reduce across the 16 lanes holding this row (lane>>4 fixed)
        part += __shfl_xor(part, 1, 64);
        part += __shfl_xor(part, 2, 64);
        part += __shfl_xor(part, 4, 64);
        part += __shfl_xor(part, 8, 64);
        if ((lane & 15) == 0)
          aux[(size_t)(bn * 4 + wc) * M + row] = part;  // column-major: coalesced
      }
    }
  }
}

// 2-phase GEMM for G3 (tiny-N, memory-bound)
template <int BM, int BN, int WN, bool RELU, bool OUT_BF16>
__global__ __launch_bounds__(256) void gemm_ff(
    const unsigned short* __restrict__ A, const unsigned short* __restrict__ Bw,
    const float* __restrict__ bias, void* __restrict__ Cptr,
    int M, int N, int K) {
  constexpr int BK = 32;
  constexpr int PTA = BM / 64;
  constexpr int PTB = BN / 64;
  __shared__ short As[BM * BK];
  __shared__ short Bs[BN * BK];

  const int t = threadIdx.x;
  const int lane = t & 63;
  const int wid = t >> 6;
  const int wr = wid / WN;
  const int wc = wid % WN;
  const int bm = blockIdx.x;
  const int bn = blockIdx.y;

  f32x4 acc[4][4] = {};
  const unsigned short* Abase = A + (size_t)bm * BM * K;
  const unsigned short* Bbase = Bw + (size_t)bn * BN * K;
  const int kIters = K / BK;
  for (int kk = 0; kk < kIters; ++kk) {
    const int k0 = kk * BK;
#pragma unroll
    for (int r = 0; r < PTB; ++r) {
      const int s = r * 256 + t;
      gll16(Bbase + (size_t)(s >> 2) * K + k0 + (s & 3) * 8, &Bs[s * 8]);
    }
#pragma unroll
    for (int r = 0; r < PTA; ++r) {
      const int s = r * 256 + t;
      gll16(Abase + (size_t)(s >> 2) * K + k0 + (s & 3) * 8, &As[s * 8]);
    }
    __syncthreads();
    short8 af[4], bfg[4];
#pragma unroll
    for (int m = 0; m < 4; ++m)
      af[m] = *(const short8*)&As[(wr * 64 + m * 16 + (lane & 15)) * BK + ((lane >> 4) * 8)];
#pragma unroll
    for (int n = 0; n < 4; ++n)
      bfg[n] = *(const short8*)&Bs[(wc * 64 + n * 16 + (lane & 15)) * BK + ((lane >> 4) * 8)];
#pragma unroll
    for (int m = 0; m < 4; ++m)
#pragma unroll
      for (int n = 0; n < 4; ++n)
        acc[m][n] = __builtin_amdgcn_mfma_f32_16x16x32_bf16(af[m], bfg[n], acc[m][n], 0, 0, 0);
    __syncthreads();
  }

#pragma unroll
  for (int m = 0; m < 4; ++m) {
#pragma unroll
    for (int j = 0; j < 4; ++j) {
      const int rl = wr * 64 + m * 16 + ((lane >> 4) << 2) + j;
      const size_t row = (size_t)bm * BM + rl;
#pragma unroll
      for (int n = 0; n < 4; ++n) {
        const int col = bn * BN + wc * 64 + n * 16 + (lane & 15);
        float v = acc[m][n][j];
        v += bias[col];
        if constexpr (RELU) v = fmaxf(v, 0.f);
        if constexpr (OUT_BF16)
          ((unsigned short*)Cptr)[row * (size_t)N + col] = f2bf(v);
        else
          ((float*)Cptr)[row * (size_t)N + col] = v;
      }
    }
  }
}

extern "C" void kernel_launch(void* const* d_in, const int* in_sizes, int n_in,
                              void* d_out, int out_size, void* d_ws, size_t ws_size,
                              hipStream_t stream) {
  const float* states = (const float*)d_in[0];
  const float* W1 = (const float*)d_in[1];
  const float* b1 = (const float*)d_in[2];
  const float* W2 = (const float*)d_in[3];
  const float* b2 = (const float*)d_in[4];
  const float* Wq = (const float*)d_in[5];
  const float* bq = (const float*)d_in[6];
  float* out = (float*)d_out;

  const int D = 1024, H1 = 2048, H2 = 1024, AO = 64;
  const int B = in_sizes[0] / D;

  unsigned short* W1b = (unsigned short*)d_ws;  // [H1][D]
  unsigned short* W2b = W1b + (size_t)H1 * D;   // [H2][H1]
  unsigned short* Wqb = W2b + (size_t)H2 * H1;  // [AO][H2]
  char* dynbase = (char*)(Wqb + (size_t)AO * H2);

  const size_t wbytes = ((size_t)H1 * D + (size_t)H2 * H1 + (size_t)AO * H2) * 2;
  size_t avail = ws_size > wbytes ? ws_size - wbytes : 0;
  // per-row: scale(4) + partial(32*4=128) + sn(D*2) + h1(H1*2) + h2(H2*2)
  const size_t per_row = 4 + 128 + (size_t)(D + H1 + H2) * 2;
  long long bc = (long long)(avail / per_row);
  bc = (bc / 256) * 256;
  if (bc <= 0) bc = 256;
  if (bc > B) bc = B;

  float* scale1 = (float*)dynbase;
  float* partial = scale1 + bc;  // [32][bc] column-major
  unsigned short* sn = (unsigned short*)(partial + (size_t)bc * 32);
  unsigned short* h1 = sn + (size_t)bc * D;
  unsigned short* h2 = h1 + (size_t)bc * H1;

  // allow 128 KiB dynamic LDS (host-side attribute set; capture-safe)
  (void)hipFuncSetAttribute((const void*)gemm_p8<true, false, true, true>,
                            hipFuncAttributeMaxDynamicSharedMemorySize, 131072);
  (void)hipFuncSetAttribute((const void*)gemm_p8<false, true, true, true>,
                            hipFuncAttributeMaxDynamicSharedMemorySize, 131072);

  cvt_w3<<<dim3(2048), dim3(256), 0, stream>>>(W1, W2, Wq, W1b, W2b, Wqb,
                                               H1 * D, H2 * H1, AO * H2);

  for (int off = 0; off < B; off += (int)bc) {
    const int cur = (B - off) < (int)bc ? (B - off) : (int)bc;
    norm_rows_f32<1024><<<dim3(cur / 4), dim3(256), 0, stream>>>(
        states + (size_t)off * D, sn, cur);
    // G1: h1 = relu(sn·W1^T + b1); writes ssq partials to `partial`
    gemm_p8<true, false, true, true>
        <<<dim3((cur / 256) * (H1 / 256)), dim3(512), 131072, stream>>>(
            sn, W1b, b1, partial, h1, cur, H1, D);
    // scale1[row] = 1/(sqrt(sum partials)+eps)
    reduce_scale<<<dim3((cur + 255) / 256), dim3(256), 0, stream>>>(
        partial, scale1, cur, (H1 / 256) * 4);
    // G2: h2 = relu(scale1·(h1·W2^T) + b2)
    gemm_p8<false, true, true, true>
        <<<dim3((cur / 256) * (H2 / 256)), dim3(512), 131072, stream>>>(
            h1, W2b, b2, scale1, h2, cur, H2, H1);
    // G3: q = h2·Wq^T + bq
    gemm_ff<256, 64, 1, false, false>
        <<<dim3(cur / 256), dim3(256), 0, stream>>>(
            h2, Wqb, bq, out + (size_t)off * AO, cur, AO, H2);
  }
}